// Round 16
// baseline (1157.849 us; speedup 1.0000x reference)
//
#include <hip/hip_runtime.h>
#include <hip/hip_bf16.h>

typedef unsigned int u32;
typedef unsigned short u16;
typedef __attribute__((ext_vector_type(8))) __bf16 bf16x8;
typedef __attribute__((ext_vector_type(8))) unsigned short u16x8;
typedef __attribute__((ext_vector_type(4))) unsigned short u16x4;
typedef __attribute__((ext_vector_type(4))) float f32x4;

#define SEQ 2048

__device__ __forceinline__ float b2f(u16 u) {
  union { u32 i; float f; } x; x.i = ((u32)u) << 16; return x.f;
}
__device__ __forceinline__ u16 f2b(float f) {
  u32 u = __float_as_uint(f);
  u = (u + 0x7fffu + ((u >> 16) & 1u)) >> 16;
  return (u16)u;
}
__device__ __forceinline__ void gload_lds16(const void* g, void* l) {
  __builtin_amdgcn_global_load_lds((const __attribute__((address_space(1))) u32*)g,
                                   (__attribute__((address_space(3))) u32*)l, 16, 0, 0);
}

// ---------------------------------------------------------------------------
// Fused fp32 -> bf16 bulk convert. Segments 0-2 (Wq/Wk/Wv) are remapped into
// a concatenated [L][3072][1024] layout.
// ---------------------------------------------------------------------------
struct CvtArgs {
  const float* src[7];
  u16* dst[7];
  u32 beg[8];
  u32 total;
};

__global__ __launch_bounds__(256) void cvt_all(CvtArgs a)
{
  for (u32 i = blockIdx.x * 256 + threadIdx.x; i < a.total; i += gridDim.x * 256) {
    int s = 0;
#pragma unroll
    for (int k = 1; k < 7; ++k) s += (i >= a.beg[k]);
    const u32 li = i - a.beg[s];
    const float* in = a.src[s];
    const float4 f0 = ((const float4*)in)[(size_t)li * 2];
    const float4 f1 = ((const float4*)in)[(size_t)li * 2 + 1];
    union { bf16x8 b; u16x8 u; } r;
    r.b[0] = (__bf16)f0.x; r.b[1] = (__bf16)f0.y;
    r.b[2] = (__bf16)f0.z; r.b[3] = (__bf16)f0.w;
    r.b[4] = (__bf16)f1.x; r.b[5] = (__bf16)f1.y;
    r.b[6] = (__bf16)f1.z; r.b[7] = (__bf16)f1.w;
    u16* d;
    if (s < 3) {
      const u32 layer = li >> 17;
      const u32 rem = li & 131071u;
      d = a.dst[s] + ((size_t)layer * 393216u + rem) * 8;
    } else {
      d = a.dst[s] + (size_t)li * 8;
    }
    *(u16x8*)d = r.u;
  }
}

// ---------------------------------------------------------------------------
// 256x256 logits GEMM — R15-proven fine 4-phase schedule.
// ---------------------------------------------------------------------------
__global__ __launch_bounds__(512, 2) void gemm256(
    const u16* __restrict__ A, const u16* __restrict__ Bt,
    float* __restrict__ C, int N, int K)
{
  __shared__ u16 As[2][256 * 64];
  __shared__ u16 Bs[2][256 * 64];
  const int tid = threadIdx.x;
  const int lane = tid & 63;
  const int wid = tid >> 6;
  const int wr = wid >> 2;
  const int wc = wid & 3;

  const int T = (int)gridDim.x;
  const int bid = (int)blockIdx.x;
  const int q8 = T >> 3, r8 = T & 7;
  const int xcd = bid & 7, base = bid >> 3;
  const int swz = (xcd < r8 ? xcd * (q8 + 1) : r8 * (q8 + 1) + (xcd - r8) * q8) + base;
  const int m0 = (swz & 7) * 256;
  const int n0 = (swz >> 3) * 256;

  f32x4 acc[8][4] = {};

  const int srow = tid >> 3;
  const int sgr = (tid & 7) ^ (srow & 7);
  const u16* gA = A + (size_t)(m0 + srow) * K + sgr * 8;
  const u16* gB = Bt + (size_t)(n0 + srow) * K + sgr * 8;
  const int dwave = wid * 512;

  const int co0 = (((lane >> 4)) ^ (lane & 7)) * 8;
  const int co1 = (((lane >> 4) + 4) ^ (lane & 7)) * 8;
  const int raA = (wr * 128 + (lane & 15)) * 64;
  const int raB = (wc * 64 + (lane & 15)) * 64;

  const int nk = K >> 6;

#pragma unroll
  for (int c = 0; c < 4; ++c) {
    gload_lds16(gA + (size_t)(c * 64) * K, &As[0][c * 4096 + dwave]);
    gload_lds16(gB + (size_t)(c * 64) * K, &Bs[0][c * 4096 + dwave]);
  }
  asm volatile("s_waitcnt vmcnt(0)" ::: "memory");
  __builtin_amdgcn_s_barrier();
  __builtin_amdgcn_sched_barrier(0);

#pragma unroll 2
  for (int t = 0; t < nk; ++t) {
    const int cb = t & 1;
    const int sb = cb ^ 1;
    const u16* Acur = &As[cb][0];
    const u16* Bcur = &Bs[cb][0];
    const bool stg = (t + 1 < nk);
    const size_t kto = (size_t)(t + 1) * 64;

    // ---------------- phase 0 ----------------
    asm volatile("s_waitcnt vmcnt(2)" ::: "memory");
    __builtin_amdgcn_s_barrier();
    bf16x8 bf[4][2];
#pragma unroll
    for (int n = 0; n < 4; ++n) {
      const int ro = raB + n * 16 * 64;
      bf[n][0] = *(const bf16x8*)&Bcur[ro + co0];
      bf[n][1] = *(const bf16x8*)&Bcur[ro + co1];
    }
    bf16x8 af[2][2];
#pragma unroll
    for (int mm = 0; mm < 2; ++mm) {
      const int ro = raA + (mm * 16) * 64;
      af[mm][0] = *(const bf16x8*)&Acur[ro + co0];
      af[mm][1] = *(const bf16x8*)&Acur[ro + co1];
    }
    if (stg) {
      gload_lds16(gB + kto, &Bs[sb][dwave]);
      gload_lds16(gB + (size_t)64 * K + kto, &Bs[sb][4096 + dwave]);
    }
    asm volatile("s_waitcnt lgkmcnt(0)" ::: "memory");
    __builtin_amdgcn_sched_barrier(0);
    __builtin_amdgcn_s_setprio(1);
#pragma unroll
    for (int mm = 0; mm < 2; ++mm)
#pragma unroll
      for (int n = 0; n < 4; ++n) {
        acc[mm][n] = __builtin_amdgcn_mfma_f32_16x16x32_bf16(af[mm][0], bf[n][0], acc[mm][n], 0, 0, 0);
        acc[mm][n] = __builtin_amdgcn_mfma_f32_16x16x32_bf16(af[mm][1], bf[n][1], acc[mm][n], 0, 0, 0);
      }
    __builtin_amdgcn_s_setprio(0);

    // ---------------- phase 1 ----------------
    __builtin_amdgcn_s_barrier();
#pragma unroll
    for (int mm = 0; mm < 2; ++mm) {
      const int ro = raA + (32 + mm * 16) * 64;
      af[mm][0] = *(const bf16x8*)&Acur[ro + co0];
      af[mm][1] = *(const bf16x8*)&Acur[ro + co1];
    }
    if (stg) {
      gload_lds16(gB + (size_t)128 * K + kto, &Bs[sb][2 * 4096 + dwave]);
      gload_lds16(gB + (size_t)192 * K + kto, &Bs[sb][3 * 4096 + dwave]);
    }
    asm volatile("s_waitcnt lgkmcnt(0)" ::: "memory");
    __builtin_amdgcn_sched_barrier(0);
    __builtin_amdgcn_s_setprio(1);
#pragma unroll
    for (int mm = 0; mm < 2; ++mm)
#pragma unroll
      for (int n = 0; n < 4; ++n) {
        acc[2 + mm][n] = __builtin_amdgcn_mfma_f32_16x16x32_bf16(af[mm][0], bf[n][0], acc[2 + mm][n], 0, 0, 0);
        acc[2 + mm][n] = __builtin_amdgcn_mfma_f32_16x16x32_bf16(af[mm][1], bf[n][1], acc[2 + mm][n], 0, 0, 0);
      }
    __builtin_amdgcn_s_setprio(0);

    // ---------------- phase 2 ----------------
    if (stg) {
      asm volatile("s_waitcnt vmcnt(4)" ::: "memory");
    } else {
      asm volatile("s_waitcnt vmcnt(0)" ::: "memory");
    }
    __builtin_amdgcn_s_barrier();
#pragma unroll
    for (int mm = 0; mm < 2; ++mm) {
      const int ro = raA + (64 + mm * 16) * 64;
      af[mm][0] = *(const bf16x8*)&Acur[ro + co0];
      af[mm][1] = *(const bf16x8*)&Acur[ro + co1];
    }
    if (stg) {
      gload_lds16(gA + kto, &As[sb][dwave]);
      gload_lds16(gA + (size_t)128 * K + kto, &As[sb][2 * 4096 + dwave]);
    }
    asm volatile("s_waitcnt lgkmcnt(0)" ::: "memory");
    __builtin_amdgcn_sched_barrier(0);
    __builtin_amdgcn_s_setprio(1);
#pragma unroll
    for (int mm = 0; mm < 2; ++mm)
#pragma unroll
      for (int n = 0; n < 4; ++n) {
        acc[4 + mm][n] = __builtin_amdgcn_mfma_f32_16x16x32_bf16(af[mm][0], bf[n][0], acc[4 + mm][n], 0, 0, 0);
        acc[4 + mm][n] = __builtin_amdgcn_mfma_f32_16x16x32_bf16(af[mm][1], bf[n][1], acc[4 + mm][n], 0, 0, 0);
      }
    __builtin_amdgcn_s_setprio(0);

    // ---------------- phase 3 ----------------
    __builtin_amdgcn_s_barrier();
#pragma unroll
    for (int mm = 0; mm < 2; ++mm) {
      const int ro = raA + (96 + mm * 16) * 64;
      af[mm][0] = *(const bf16x8*)&Acur[ro + co0];
      af[mm][1] = *(const bf16x8*)&Acur[ro + co1];
    }
    if (stg) {
      gload_lds16(gA + (size_t)64 * K + kto, &As[sb][4096 + dwave]);
      gload_lds16(gA + (size_t)192 * K + kto, &As[sb][3 * 4096 + dwave]);
    }
    asm volatile("s_waitcnt lgkmcnt(0)" ::: "memory");
    __builtin_amdgcn_sched_barrier(0);
    __builtin_amdgcn_s_setprio(1);
#pragma unroll
    for (int mm = 0; mm < 2; ++mm)
#pragma unroll
      for (int n = 0; n < 4; ++n) {
        acc[6 + mm][n] = __builtin_amdgcn_mfma_f32_16x16x32_bf16(af[mm][0], bf[n][0], acc[6 + mm][n], 0, 0, 0);
        acc[6 + mm][n] = __builtin_amdgcn_mfma_f32_16x16x32_bf16(af[mm][1], bf[n][1], acc[6 + mm][n], 0, 0, 0);
      }
    __builtin_amdgcn_s_setprio(0);
    __builtin_amdgcn_sched_barrier(0);
  }

  const int crow = m0 + wr * 128 + ((lane >> 4) << 2);
  const int ccol = n0 + wc * 64 + (lane & 15);
#pragma unroll
  for (int m = 0; m < 8; ++m)
#pragma unroll
    for (int n = 0; n < 4; ++n)
#pragma unroll
      for (int j = 0; j < 4; ++j)
        C[(size_t)(crow + m * 16 + j) * N + ccol + n * 16] = acc[m][n][j];
}

// ---------------------------------------------------------------------------
// 128x128 layer GEMM — R16: fine 4-phase schedule (same ledger as gemm256).
// A staging call c covers rows c*32..c*32+31; phases 0,1 read A c0,c2
// (rows 0-31 / 64-95 across waves); phases 2,3 read A c1,c3. B read at p0.
// Stage order t+1: p0 {B c0,c1}, p1 {B c2,c3}, p2 {A c0,c2}, p3 {A c1,c3}.
// p0: vmcnt(2)+bar; p2: vmcnt(stg?4:0)+bar.
// EPI 0: bf16 partial store to (u16*)C0 + blockIdx.z * (2048*1024)
// EPI 1: QKV head-major bf16 from concat [3072][1024] weights
// EPI 2: bf16 gelu(acc + bias[col])
// ---------------------------------------------------------------------------
template <int EPI>
__global__ __launch_bounds__(256, 2) void gemm128p(
    const u16* __restrict__ A, const u16* __restrict__ Bt,
    void* __restrict__ C0, void* __restrict__ C1, void* __restrict__ C2,
    const float* __restrict__ bias, int N, int K)
{
  __shared__ u16 As[2][128 * 64];
  __shared__ u16 Bs[2][128 * 64];
  const int tid = threadIdx.x;
  const int lane = tid & 63;
  const int wid = tid >> 6;
  const int wr = wid >> 1;
  const int wc = wid & 1;

  const int T = (int)gridDim.x;
  const int bid = (int)blockIdx.x;
  const int q8 = T >> 3, r8 = T & 7;
  const int xcd = bid & 7, base = bid >> 3;
  const int swz = (xcd < r8 ? xcd * (q8 + 1) : r8 * (q8 + 1) + (xcd - r8) * q8) + base;
  const int m0 = (swz & 15) * 128;
  const int n0 = (swz >> 4) * 128;

  const int kchunk = K / (int)gridDim.z;
  const int kbeg = (int)blockIdx.z * kchunk;
  const int nk = kchunk >> 6;

  f32x4 acc[4][4] = {};

  const int srow = tid >> 3;
  const int sgr = (tid & 7) ^ (srow & 7);
  const u16* gA = A + (size_t)(m0 + srow) * K + kbeg + sgr * 8;
  const u16* gB = Bt + (size_t)(n0 + srow) * K + kbeg + sgr * 8;
  const int dwave = wid * 512;

  const int co0 = (((lane >> 4)) ^ (lane & 7)) * 8;
  const int co1 = (((lane >> 4) + 4) ^ (lane & 7)) * 8;
  const int raA = (wr * 64 + (lane & 15)) * 64;
  const int raB = (wc * 64 + (lane & 15)) * 64;

  // prologue: stage tile 0 into buf 0 (8 calls), full drain
#pragma unroll
  for (int c = 0; c < 4; ++c) {
    gload_lds16(gA + (size_t)(c * 32) * K, &As[0][c * 2048 + dwave]);
    gload_lds16(gB + (size_t)(c * 32) * K, &Bs[0][c * 2048 + dwave]);
  }
  asm volatile("s_waitcnt vmcnt(0)" ::: "memory");
  __builtin_amdgcn_s_barrier();
  __builtin_amdgcn_sched_barrier(0);

#pragma unroll 2
  for (int t = 0; t < nk; ++t) {
    const int cb = t & 1;
    const int sb = cb ^ 1;
    const u16* Acur = &As[cb][0];
    const u16* Bcur = &Bs[cb][0];
    const bool stg = (t + 1 < nk);
    const size_t kto = (size_t)(t + 1) * 64;

    // ---------------- phase 0 ----------------
    asm volatile("s_waitcnt vmcnt(2)" ::: "memory");
    __builtin_amdgcn_s_barrier();
    bf16x8 bf[4][2];
#pragma unroll
    for (int n = 0; n < 4; ++n) {
      const int ro = raB + n * 16 * 64;
      bf[n][0] = *(const bf16x8*)&Bcur[ro + co0];
      bf[n][1] = *(const bf16x8*)&Bcur[ro + co1];
    }
    bf16x8 af[2];
    {
      const int ro = raA;
      af[0] = *(const bf16x8*)&Acur[ro + co0];
      af[1] = *(const bf16x8*)&Acur[ro + co1];
    }
    if (stg) {
      gload_lds16(gB + kto, &Bs[sb][dwave]);
      gload_lds16(gB + (size_t)32 * K + kto, &Bs[sb][2048 + dwave]);
    }
    asm volatile("s_waitcnt lgkmcnt(0)" ::: "memory");
    __builtin_amdgcn_sched_barrier(0);
    __builtin_amdgcn_s_setprio(1);
#pragma unroll
    for (int n = 0; n < 4; ++n) {
      acc[0][n] = __builtin_amdgcn_mfma_f32_16x16x32_bf16(af[0], bf[n][0], acc[0][n], 0, 0, 0);
      acc[0][n] = __builtin_amdgcn_mfma_f32_16x16x32_bf16(af[1], bf[n][1], acc[0][n], 0, 0, 0);
    }
    __builtin_amdgcn_s_setprio(0);

    // ---------------- phase 1 ----------------
    __builtin_amdgcn_s_barrier();
    {
      const int ro = raA + 16 * 64;
      af[0] = *(const bf16x8*)&Acur[ro + co0];
      af[1] = *(const bf16x8*)&Acur[ro + co1];
    }
    if (stg) {
      gload_lds16(gB + (size_t)64 * K + kto, &Bs[sb][2 * 2048 + dwave]);
      gload_lds16(gB + (size_t)96 * K + kto, &Bs[sb][3 * 2048 + dwave]);
    }
    asm volatile("s_waitcnt lgkmcnt(0)" ::: "memory");
    __builtin_amdgcn_sched_barrier(0);
    __builtin_amdgcn_s_setprio(1);
#pragma unroll
    for (int n = 0; n < 4; ++n) {
      acc[1][n] = __builtin_amdgcn_mfma_f32_16x16x32_bf16(af[0], bf[n][0], acc[1][n], 0, 0, 0);
      acc[1][n] = __builtin_amdgcn_mfma_f32_16x16x32_bf16(af[1], bf[n][1], acc[1][n], 0, 0, 0);
    }
    __builtin_amdgcn_s_setprio(0);

    // ---------------- phase 2 ----------------
    if (stg) {
      asm volatile("s_waitcnt vmcnt(4)" ::: "memory");
    } else {
      asm volatile("s_waitcnt vmcnt(0)" ::: "memory");
    }
    __builtin_amdgcn_s_barrier();
    {
      const int ro = raA + 32 * 64;
      af[0] = *(const bf16x8*)&Acur[ro + co0];
      af[1] = *(const bf16x8*)&Acur[ro + co1];
    }
    if (stg) {
      gload_lds16(gA + kto, &As[sb][dwave]);
      gload_lds16(gA + (size_t)64 * K + kto, &As[sb][2 * 2048 + dwave]);
    }
    asm volatile("s_waitcnt lgkmcnt(0)" ::: "memory");
    __builtin_amdgcn_sched_barrier(0);
    __builtin_amdgcn_s_setprio(1);
#pragma unroll
    for (int n = 0; n < 4; ++n) {
      acc[2][n] = __builtin_amdgcn_mfma_f32_16x16x32_bf16(af[0], bf[n][0], acc[2][n], 0, 0, 0);
      acc[2][n] = __builtin_amdgcn_mfma_f32_16x16x32_bf16(af[1], bf[n][1], acc[2][n], 0, 0, 0);
    }
    __builtin_amdgcn_s_setprio(0);

    // ---------------- phase 3 ----------------
    __builtin_amdgcn_s_barrier();
    {
      const int ro = raA + 48 * 64;
      af[0] = *(const bf16x8*)&Acur[ro + co0];
      af[1] = *(const bf16x8*)&Acur[ro + co1];
    }
    if (stg) {
      gload_lds16(gA + (size_t)32 * K + kto, &As[sb][2048 + dwave]);
      gload_lds16(gA + (size_t)96 * K + kto, &As[sb][3 * 2048 + dwave]);
    }
    asm volatile("s_waitcnt lgkmcnt(0)" ::: "memory");
    __builtin_amdgcn_sched_barrier(0);
    __builtin_amdgcn_s_setprio(1);
#pragma unroll
    for (int n = 0; n < 4; ++n) {
      acc[3][n] = __builtin_amdgcn_mfma_f32_16x16x32_bf16(af[0], bf[n][0], acc[3][n], 0, 0, 0);
      acc[3][n] = __builtin_amdgcn_mfma_f32_16x16x32_bf16(af[1], bf[n][1], acc[3][n], 0, 0, 0);
    }
    __builtin_amdgcn_s_setprio(0);
    __builtin_amdgcn_sched_barrier(0);
  }

  const int z = (int)blockIdx.z;
#pragma unroll
  for (int m = 0; m < 4; ++m) {
    const int rowb = m0 + wr * 64 + m * 16 + ((lane >> 4) << 2);
#pragma unroll
    for (int n = 0; n < 4; ++n) {
      const int col = n0 + wc * 64 + n * 16 + (lane & 15);
#pragma unroll
      for (int j = 0; j < 4; ++j) {
        const int r = rowb + j;
        float v = acc[m][n][j];
        if (EPI == 0) {
          u16* outp = (u16*)C0 + (size_t)z * (2048u * 1024u);
          outp[(size_t)r * N + col] = f2b(v);
        } else if (EPI == 1) {
          const int which = col >> 10;
          const int ci = col & 1023;
          u16* outp = (u16*)((which == 0) ? C0 : (which == 1) ? C1 : C2);
          outp[((size_t)(ci >> 6) * SEQ + r) * 64 + (ci & 63)] = f2b(v);
        } else {
          float xx = v + bias[col];
          float ge = 0.5f * xx * (1.0f + erff(xx * 0.70710678118654752f));
          ((u16*)C0)[(size_t)r * N + col] = f2b(ge);
        }
      }
    }
  }
}

// ---------------------------------------------------------------------------
// Fallback logits GEMM (fp32 B, BK=32) if emb_bf16 doesn't fit ws.
// ---------------------------------------------------------------------------
__global__ __launch_bounds__(256) void gemm_f32b(
    const u16* __restrict__ A, const float* __restrict__ Bt,
    float* __restrict__ C0, int N, int K)
{
  __shared__ u16 As[128 * 32];
  __shared__ u16 Bs[128 * 32];
  const int tid = threadIdx.x;
  const int lane = tid & 63;
  const int w = tid >> 6;
  const int wr = w >> 1;
  const int wc = w & 1;

  const int T = (int)gridDim.x;
  const int bid = (int)blockIdx.x;
  const int q8 = T >> 3, r8 = T & 7;
  const int xcd = bid & 7, base = bid >> 3;
  int swz = (xcd < r8 ? xcd * (q8 + 1) : r8 * (q8 + 1) + (xcd - r8) * q8) + base;
  const int m0 = (swz & 15) * 128;
  const int n0 = (swz >> 4) * 128;

  f32x4 acc[4][4] = {};
  const u16* ga0 = A + (size_t)(m0 + w * 32 + (lane >> 2)) * K + (lane & 3) * 8;
  u16* la = &As[(w * 32) * 32];
  const float* gb32 = Bt + (size_t)(n0 + (tid >> 1)) * K + (tid & 1) * 16;
  u16* lbw = &Bs[(tid >> 1) * 32 + (tid & 1) * 16];

  for (int kt = 0; kt < K; kt += 32) {
    __syncthreads();
    gload_lds16(ga0 + kt, la);
    gload_lds16(ga0 + kt + 16 * K, la + 16 * 32);
    {
      const float4 f0 = *(const float4*)(gb32 + kt);
      const float4 f1 = *(const float4*)(gb32 + kt + 4);
      const float4 f2 = *(const float4*)(gb32 + kt + 8);
      const float4 f3 = *(const float4*)(gb32 + kt + 12);
      union { bf16x8 b; u16x8 u; } lo, hi;
      lo.b[0] = (__bf16)f0.x; lo.b[1] = (__bf16)f0.y;
      lo.b[2] = (__bf16)f0.z; lo.b[3] = (__bf16)f0.w;
      lo.b[4] = (__bf16)f1.x; lo.b[5] = (__bf16)f1.y;
      lo.b[6] = (__bf16)f1.z; lo.b[7] = (__bf16)f1.w;
      hi.b[0] = (__bf16)f2.x; hi.b[1] = (__bf16)f2.y;
      hi.b[2] = (__bf16)f2.z; hi.b[3] = (__bf16)f2.w;
      hi.b[4] = (__bf16)f3.x; hi.b[5] = (__bf16)f3.y;
      hi.b[6] = (__bf16)f3.z; hi.b[7] = (__bf16)f3.w;
      *(u16x8*)lbw = lo.u;
      *(u16x8*)(lbw + 8) = hi.u;
    }
    asm volatile("s_waitcnt vmcnt(0)" ::: "memory");
    __syncthreads();
    bf16x8 af[4], bfr[4];
#pragma unroll
    for (int m = 0; m < 4; ++m)
      af[m] = *(const bf16x8*)&As[(wr * 64 + m * 16 + (lane & 15)) * 32 + (lane >> 4) * 8];
#pragma unroll
    for (int n = 0; n < 4; ++n)
      bfr[n] = *(const bf16x8*)&Bs[(wc * 64 + n * 16 + (lane & 15)) * 32 + (lane >> 4) * 8];
#pragma unroll
    for (int m = 0; m < 4; ++m)
#pragma unroll
      for (int n = 0; n < 4; ++n)
        acc[m][n] = __builtin_amdgcn_mfma_f32_16x16x32_bf16(af[m], bfr[n], acc[m][n], 0, 0, 0);
  }

#pragma unroll
  for (int m = 0; m < 4; ++m) {
    const int rowb = m0 + wr * 64 + m * 16 + ((lane >> 4) << 2);
#pragma unroll
    for (int n = 0; n < 4; ++n) {
      const int col = n0 + wc * 64 + n * 16 + (lane & 15);
#pragma unroll
      for (int j = 0; j < 4; ++j)
        C0[(size_t)(rowb + j) * N + col] = acc[m][n][j];
    }
  }
}

// ---------------------------------------------------------------------------
// LayerNorm (plain): fp32 x[row][1024] -> bf16 h
// ---------------------------------------------------------------------------
__global__ __launch_bounds__(256) void ln_kernel(const float* __restrict__ x,
    const float* __restrict__ g, const float* __restrict__ b, u16* __restrict__ out)
{
  const int row = blockIdx.x;
  const int tid = threadIdx.x;
  const float4 v = ((const float4*)(x + (size_t)row * 1024))[tid];
  float s = v.x + v.y + v.z + v.w;
  float sq = v.x * v.x + v.y * v.y + v.z * v.z + v.w * v.w;
#pragma unroll
  for (int o = 1; o < 64; o <<= 1) { s += __shfl_xor(s, o); sq += __shfl_xor(sq, o); }
  __shared__ float ss[4], ssq[4];
  if ((tid & 63) == 0) { ss[tid >> 6] = s; ssq[tid >> 6] = sq; }
  __syncthreads();
  s = ss[0] + ss[1] + ss[2] + ss[3];
  sq = ssq[0] + ssq[1] + ssq[2] + ssq[3];
  const float mean = s * (1.0f / 1024.0f);
  const float var = sq * (1.0f / 1024.0f) - mean * mean;
  const float rstd = rsqrtf(var + 1e-5f);
  const int c = tid * 4;
  u16* o4 = out + (size_t)row * 1024 + c;
  const float4 gg = ((const float4*)g)[tid];
  const float4 bb = ((const float4*)b)[tid];
  o4[0] = f2b((v.x - mean) * rstd * gg.x + bb.x);
  o4[1] = f2b((v.y - mean) * rstd * gg.y + bb.y);
  o4[2] = f2b((v.z - mean) * rstd * gg.z + bb.z);
  o4[3] = f2b((v.w - mean) * rstd * gg.w + bb.w);
}

// ---------------------------------------------------------------------------
// Fused residual + LayerNorm, 4 bf16 split-K partials.
// ---------------------------------------------------------------------------
__global__ __launch_bounds__(256) void ln_res4(float* __restrict__ x,
    const u16* __restrict__ P, const float* __restrict__ bias,
    const float* __restrict__ g, const float* __restrict__ b,
    u16* __restrict__ out)
{
  const int row = blockIdx.x;
  const int tid = threadIdx.x;
  const size_t off = (size_t)row * 1024;
  float4 v = ((const float4*)(x + off))[tid];
#pragma unroll
  for (int j = 0; j < 4; ++j) {
    const u16x4 a = *(const u16x4*)(P + (size_t)j * 2048 * 1024 + off + tid * 4);
    v.x += b2f(a[0]); v.y += b2f(a[1]); v.z += b2f(a[2]); v.w += b2f(a[3]);
  }
  if (bias != nullptr) {
    const float4 bi = ((const float4*)bias)[tid];
    v.x += bi.x; v.y += bi.y; v.z += bi.z; v.w += bi.w;
  }
  ((float4*)(x + off))[tid] = v;
  float s = v.x + v.y + v.z + v.w;
  float sq = v.x * v.x + v.y * v.y + v.z * v.z + v.w * v.w;
#pragma unroll
  for (int o = 1; o < 64; o <<= 1) { s += __shfl_xor(s, o); sq += __shfl_xor(sq, o); }
  __shared__ float ss[4], ssq[4];
  if ((tid & 63) == 0) { ss[tid >> 6] = s; ssq[tid >> 6] = sq; }
  __syncthreads();
  s = ss[0] + ss[1] + ss[2] + ss[3];
  sq = ssq[0] + ssq[1] + ssq[2] + ssq[3];
  const float mean = s * (1.0f / 1024.0f);
  const float var = sq * (1.0f / 1024.0f) - mean * mean;
  const float rstd = rsqrtf(var + 1e-5f);
  const int c = tid * 4;
  u16* o4 = out + off + c;
  const float4 gg = ((const float4*)g)[tid];
  const float4 bb = ((const float4*)b)[tid];
  o4[0] = f2b((v.x - mean) * rstd * gg.x + bb.x);
  o4[1] = f2b((v.y - mean) * rstd * gg.y + bb.y);
  o4[2] = f2b((v.z - mean) * rstd * gg.z + bb.z);
  o4[3] = f2b((v.w - mean) * rstd * gg.w + bb.w);
}

// ---------------------------------------------------------------------------
// Embedding gather: x[s][d] = emb_fp32[ids[s]][d]
// ---------------------------------------------------------------------------
__global__ __launch_bounds__(256) void gather_kernel(const int* __restrict__ ids,
    const float* __restrict__ emb, float* __restrict__ x)
{
  const int srow = blockIdx.x;
  const int tid = threadIdx.x;
  const int id = ids[srow];
  ((float4*)(x + (size_t)srow * 1024))[tid] =
      ((const float4*)(emb + (size_t)id * 1024))[tid];
}

// ---------------------------------------------------------------------------
// Flash attention w/ ALiBi + causal (R11 config: 512 blocks x 128 threads).
// ---------------------------------------------------------------------------
__global__ __launch_bounds__(128) void attn_kernel(
    const u16* __restrict__ q, const u16* __restrict__ k, const u16* __restrict__ v,
    const float* __restrict__ slopes, u16* __restrict__ out)
{
  const int bid = (int)blockIdx.x;
  const int h = bid & 15;
  const int qi = 31 - (bid >> 4);
  const int q0 = qi * 64;
  const int tid = threadIdx.x;
  const int lane = tid & 63;
  const int w = tid >> 6;
  const float slope = slopes[h];

  __shared__ u16 Ks[2][64 * 32];
  __shared__ u16 Vt[64][72];
  __shared__ u16 Pl[2][32][72];

  const u16* qb = q + ((size_t)h * SEQ + q0 + w * 32) * 64;
  bf16x8 qf[2][2];
#pragma unroll
  for (int m = 0; m < 2; ++m)
#pragma unroll
    for (int kk = 0; kk < 2; ++kk)
      qf[m][kk] = *(const bf16x8*)(qb + (m * 16 + (lane & 15)) * 64 + kk * 32 + (lane >> 4) * 8);

  f32x4 o_acc[2][4] = {};
  float mrun[2][4], lrun[2][4];
#pragma unroll
  for (int m = 0; m < 2; ++m)
#pragma unroll
    for (int j = 0; j < 4; ++j) { mrun[m][j] = -1e30f; lrun[m][j] = 0.0f; }

  const int ntiles = qi + 1;
  const int wmaxrow = q0 + w * 32 + 31;

  const int ksl = (lane & 3) ^ ((lane >> 2) & 3);
  const u16* gk0 = k + ((size_t)h * SEQ + (lane >> 2)) * 64 + w * 32 + ksl * 8;
  u16* lk = &Ks[w][0];
  const u16* gv0 = v + ((size_t)h * SEQ + lane) * 64 + w * 32;
  const int krd = ((lane >> 4) ^ (lane & 3)) * 8;

  for (int t = 0; t < ntiles; ++t) {
    const int j0 = t << 6;
    __syncthreads();
#pragma unroll
    for (int r = 0; r < 4; ++r)
      gload_lds16(gk0 + (size_t)(j0 + r * 16) * 64, lk + r * 16 * 32);
    {
      const u16* gvp = gv0 + (size_t)j0 * 64;
      u16x8 v0 = *(const u16x8*)gvp;
      u16x8 v1 = *(const u16x8*)(gvp + 8);
      u16x8 v2 = *(const u16x8*)(gvp + 16);
      u16x8 v3 = *(const u16x8*)(gvp + 24);
      const int d0 = w * 32;
#pragma unroll
      for (int i = 0; i < 8; ++i) Vt[d0 + i][lane] = v0[i];
#pragma unroll
      for (int i = 0; i < 8; ++i) Vt[d0 + 8 + i][lane] = v1[i];
#pragma unroll
      for (int i = 0; i < 8; ++i) Vt[d0 + 16 + i][lane] = v2[i];
#pragma unroll
      for (int i = 0; i < 8; ++i) Vt[d0 + 24 + i][lane] = v3[i];
    }
    asm volatile("s_waitcnt vmcnt(0)" ::: "memory");
    __syncthreads();

    if (wmaxrow >= j0) {
      f32x4 s[2][4] = {};
      __builtin_amdgcn_s_setprio(1);
#pragma unroll
      for (int kk = 0; kk < 2; ++kk) {
        bf16x8 kf[4];
#pragma unroll
        for (int n = 0; n < 4; ++n)
          kf[n] = *(const bf16x8*)&Ks[kk][(n * 16 + (lane & 15)) * 32 + krd];
#pragma unroll
        for (int m = 0; m < 2; ++m)
#pragma unroll
          for (int n = 0; n < 4; ++n)
            s[m][n] = __builtin_amdgcn_mfma_f32_16x16x32_bf16(qf[m][kk], kf[n], s[m][n], 0, 0, 0);
      }
      __builtin_amdgcn_s_setprio(0);
      const int rq = q0 + w * 32 + ((lane >> 4) << 2);
      const int ck = j0 + (lane & 15);
#pragma unroll
      for (int m = 0; m < 2; ++m) {
#pragma unroll
        for (int j = 0; j < 4; ++j) {
          const int qi2 = rq + m * 16 + j;
          float mx = -1e30f;
#pragma unroll
          for (int n = 0; n < 4; ++n) {
            const int kj = ck + n * 16;
            float val = s[m][n][j] * 0.125f - slope * (float)(kj - qi2);
            val = (kj <= qi2) ? val : -1e30f;
            s[m][n][j] = val;
            mx = fmaxf(mx, val);
          }
#pragma unroll
          for (int o = 1; o < 16; o <<= 1) mx = fmaxf(mx, __shfl_xor(mx, o));
          const float mnew = fmaxf(mrun[m][j], mx);
          const float alpha = __expf(mrun[m][j] - mnew);
          mrun[m][j] = mnew;
          float rs = 0.0f;
          const int prow = m * 16 + ((lane >> 4) << 2) + j;
#pragma unroll
          for (int n = 0; n < 4; ++n) {
            const float p = __expf(s[m][n][j] - mnew);
            rs += p;
            Pl[w][prow][n * 16 + (lane & 15)] = f2b(p);
          }
#pragma unroll
          for (int o = 1; o < 16; o <<= 1) rs += __shfl_xor(rs, o);
          lrun[m][j] = lrun[m][j] * alpha + rs;
#pragma unroll
          for (int n = 0; n < 4; ++n) o_acc[m][n][j] *= alpha;
        }
      }
      __builtin_amdgcn_s_setprio(1);
#pragma unroll
      for (int kk = 0; kk < 2; ++kk) {
        bf16x8 pf[2], vf[4];
#pragma unroll
        for (int m = 0; m < 2; ++m)
          pf[m] = *(const bf16x8*)&Pl[w][m * 16 + (lane & 15)][kk * 32 + (lane >> 4) * 8];
#pragma unroll
        for (int n = 0; n < 4; ++n)
          vf[n] = *(const bf16x8*)&Vt[n * 16 + (lane & 15)][kk * 32 + (lane >> 4) * 8];
#pragma unroll
        for (int m = 0; m < 2; ++m)
#pragma unroll
          for (int n = 0; n < 4; ++n)
            o_acc[m][n] = __builtin_amdgcn_mfma_f32_16x16x32_bf16(pf[m], vf[n], o_acc[m][n], 0, 0, 0);
      }
      __builtin_amdgcn_s_setprio(0);
    }
  }

#pragma unroll
  for (int m = 0; m < 2; ++m) {
    const int sbase = q0 + w * 32 + m * 16 + ((lane >> 4) << 2);
#pragma unroll
    for (int n = 0; n < 4; ++n) {
      const int d = h * 64 + n * 16 + (lane & 15);
#pragma unroll
      for (int j = 0; j < 4; ++j)
        out[(size_t)(sbase + j) * 1024 + d] = f2b(o_acc[m][n][j] / lrun[m][j]);
    }
  }
}

// ---------------------------------------------------------------------------
extern "C" void kernel_launch(void* const* d_in, const int* in_sizes, int n_in,
                              void* d_out, int out_size, void* d_ws, size_t ws_size,
                              hipStream_t stream)
{
  (void)in_sizes; (void)n_in; (void)out_size;
  const int* ids = (const int*)d_in[0];
  const float* emb = (const float*)d_in[1];
  const float* slopes = (const float*)d_in[2];
  const float* Wq = (const float*)d_in[3];
  const float* Wk = (const float*)d_in[4];
  const float* Wv = (const float*)d_in[5];
  const float* Wo = (const float*)d_in[6];
  const float* W1 = (const float*)d_in[7];
  const float* b1 = (const float*)d_in[8];
  const float* W2 = (const float*)d_in[9];
  const float* b2 = (const float*)d_in[10];
  const float* g1 = (const float*)d_in[11];
  const float* be1 = (const float*)d_in[12];
  const float* g2 = (const float*)d_in[13];
  const float* be2 = (const float*)d_in[14];
  const float* gf = (const float*)d_in[15];
  const float* bfin = (const float*)d_in[16];

  char* ob = (char*)d_out;
  float* x    = (float*)ob;                          // 8 MB fp32 residual
  u16* qb     = (u16*)(ob + (size_t)( 8u << 20));    // 4 MB
  u16* kb     = (u16*)(ob + (size_t)(12u << 20));    // 4 MB
  u16* vb     = (u16*)(ob + (size_t)(16u << 20));    // 4 MB
  u16* attn   = (u16*)(ob + (size_t)(20u << 20));    // 4 MB
  u16* ff     = (u16*)(ob + (size_t)(24u << 20));    // 16 MB
  u16* Wqkv_b = (u16*)(ob + (size_t)( 40u << 20));   // 24 MB  [4][3072][1024]
  u16* Wo_b   = (u16*)(ob + (size_t)( 64u << 20));   // 8 MB
  u16* W1_b   = (u16*)(ob + (size_t)( 72u << 20));   // 32 MB
  u16* W2_b   = (u16*)(ob + (size_t)(104u << 20));   // 32 MB
  u16* P      = (u16*)(ob + (size_t)(136u << 20));   // 16 MB: 4 bf16 partials
  u16* h      = (u16*)d_ws;                          // 4 MB
  const size_t emb_b_need = (size_t)(4u << 20) + (size_t)32000 * 1024 * 2;
  const bool emb_fits = ws_size >= emb_b_need;
  u16* emb_b = (u16*)((char*)d_ws + (4u << 20));
  float* logits = (float*)d_out;

  {
    CvtArgs a;
    const u32 wsz = 4 * 1024 * 1024 / 8;
    const u32 fsz = 16 * 1024 * 1024 / 8;
    const u32 esz = 32000 * 1024 / 8;
    a.src[0] = Wq; a.dst[0] = Wqkv_b;
    a.src[1] = Wk; a.dst[1] = Wqkv_b + 1024 * 1024;
    a.src[2] = Wv; a.dst[2] = Wqkv_b + 2 * 1024 * 1024;
    a.src[3] = Wo; a.dst[3] = Wo_b;
    a.src[4] = W1; a.dst[4] = W1_b;
    a.src[5] = W2; a.dst[5] = W2_b;
    a.src[6] = emb; a.dst[6] = emb_b;
    a.beg[0] = 0;
    a.beg[1] = wsz;      a.beg[2] = 2 * wsz;  a.beg[3] = 3 * wsz;
    a.beg[4] = 4 * wsz;  a.beg[5] = 4 * wsz + fsz;  a.beg[6] = 4 * wsz + 2 * fsz;
    a.beg[7] = a.beg[6] + esz;
    a.total = emb_fits ? a.beg[7] : a.beg[6];
    cvt_all<<<2048, 256, 0, stream>>>(a);
  }

  gather_kernel<<<2048, 256, 0, stream>>>(ids, emb, x);
  ln_kernel<<<2048, 256, 0, stream>>>(x, g1, be1, h);

  for (int l = 0; l < 4; ++l) {
    const size_t wqkv = (size_t)l * 3072 * 1024;
    const size_t wo = (size_t)l * 1024 * 1024;
    const size_t wf = (size_t)l * 4096 * 1024;
    gemm128p<1><<<dim3(384, 1, 1), 256, 0, stream>>>(h, Wqkv_b + wqkv,
        qb, kb, vb, nullptr, 3072, 1024);
    attn_kernel<<<dim3(512, 1, 1), 128, 0, stream>>>(qb, kb, vb, slopes, attn);
    gemm128p<0><<<dim3(128, 1, 4), 256, 0, stream>>>(attn, Wo_b + wo,
        P, nullptr, nullptr, nullptr, 1024, 1024);
    ln_res4<<<2048, 256, 0, stream>>>(x, P, nullptr,
        g2 + l * 1024, be2 + l * 1024, h);
    gemm128p<2><<<dim3(512, 1, 1), 256, 0, stream>>>(h, W1_b + wf,
        ff, nullptr, nullptr, b1 + l * 4096, 4096, 1024);
    gemm128p<0><<<dim3(128, 1, 4), 256, 0, stream>>>(ff, W2_b + wf,
        P, nullptr, nullptr, nullptr, 1024, 4096);
    if (l < 3) {
      ln_res4<<<2048, 256, 0, stream>>>(x, P, b2 + l * 1024,
          g1 + (l + 1) * 1024, be1 + (l + 1) * 1024, h);
    } else {
      ln_res4<<<2048, 256, 0, stream>>>(x, P, b2 + l * 1024, gf, bfin, h);
    }
  }

  if (emb_fits) {
    gemm256<<<dim3(1000, 1, 1), 512, 0, stream>>>(h, emb_b, logits, 32000, 1024);
  } else {
    gemm_f32b<<<dim3(4000, 1, 1), 256, 0, stream>>>(h, emb, logits, 32000, 1024);
  }
}

// Round 17
// 1143.597 us; speedup vs baseline: 1.0125x; 1.0125x over previous
//
#include <hip/hip_runtime.h>
#include <hip/hip_bf16.h>

typedef unsigned int u32;
typedef unsigned short u16;
typedef __attribute__((ext_vector_type(8))) __bf16 bf16x8;
typedef __attribute__((ext_vector_type(8))) unsigned short u16x8;
typedef __attribute__((ext_vector_type(4))) unsigned short u16x4;
typedef __attribute__((ext_vector_type(4))) float f32x4;

#define SEQ 2048

__device__ __forceinline__ float b2f(u16 u) {
  union { u32 i; float f; } x; x.i = ((u32)u) << 16; return x.f;
}
__device__ __forceinline__ u16 f2b(float f) {
  u32 u = __float_as_uint(f);
  u = (u + 0x7fffu + ((u >> 16) & 1u)) >> 16;
  return (u16)u;
}
__device__ __forceinline__ void gload_lds16(const void* g, void* l) {
  __builtin_amdgcn_global_load_lds((const __attribute__((address_space(1))) u32*)g,
                                   (__attribute__((address_space(3))) u32*)l, 16, 0, 0);
}

// ---------------------------------------------------------------------------
// Fused fp32 -> bf16 bulk convert. Segments 0-2 (Wq/Wk/Wv) are remapped into
// a concatenated [L][3072][1024] layout.
// ---------------------------------------------------------------------------
struct CvtArgs {
  const float* src[7];
  u16* dst[7];
  u32 beg[8];
  u32 total;
};

__global__ __launch_bounds__(256) void cvt_all(CvtArgs a)
{
  for (u32 i = blockIdx.x * 256 + threadIdx.x; i < a.total; i += gridDim.x * 256) {
    int s = 0;
#pragma unroll
    for (int k = 1; k < 7; ++k) s += (i >= a.beg[k]);
    const u32 li = i - a.beg[s];
    const float* in = a.src[s];
    const float4 f0 = ((const float4*)in)[(size_t)li * 2];
    const float4 f1 = ((const float4*)in)[(size_t)li * 2 + 1];
    union { bf16x8 b; u16x8 u; } r;
    r.b[0] = (__bf16)f0.x; r.b[1] = (__bf16)f0.y;
    r.b[2] = (__bf16)f0.z; r.b[3] = (__bf16)f0.w;
    r.b[4] = (__bf16)f1.x; r.b[5] = (__bf16)f1.y;
    r.b[6] = (__bf16)f1.z; r.b[7] = (__bf16)f1.w;
    u16* d;
    if (s < 3) {
      const u32 layer = li >> 17;
      const u32 rem = li & 131071u;
      d = a.dst[s] + ((size_t)layer * 393216u + rem) * 8;
    } else {
      d = a.dst[s] + (size_t)li * 8;
    }
    *(u16x8*)d = r.u;
  }
}

// ---------------------------------------------------------------------------
// 256x256 logits GEMM — R15-proven fine 4-phase schedule.
// Epilogue uses nontemporal stores (streaming 257 MB write, no L2 allocate).
// ---------------------------------------------------------------------------
__global__ __launch_bounds__(512, 2) void gemm256(
    const u16* __restrict__ A, const u16* __restrict__ Bt,
    float* __restrict__ C, int N, int K)
{
  __shared__ u16 As[2][256 * 64];
  __shared__ u16 Bs[2][256 * 64];
  const int tid = threadIdx.x;
  const int lane = tid & 63;
  const int wid = tid >> 6;
  const int wr = wid >> 2;
  const int wc = wid & 3;

  const int T = (int)gridDim.x;
  const int bid = (int)blockIdx.x;
  const int q8 = T >> 3, r8 = T & 7;
  const int xcd = bid & 7, base = bid >> 3;
  const int swz = (xcd < r8 ? xcd * (q8 + 1) : r8 * (q8 + 1) + (xcd - r8) * q8) + base;
  const int m0 = (swz & 7) * 256;
  const int n0 = (swz >> 3) * 256;

  f32x4 acc[8][4] = {};

  const int srow = tid >> 3;
  const int sgr = (tid & 7) ^ (srow & 7);
  const u16* gA = A + (size_t)(m0 + srow) * K + sgr * 8;
  const u16* gB = Bt + (size_t)(n0 + srow) * K + sgr * 8;
  const int dwave = wid * 512;

  const int co0 = (((lane >> 4)) ^ (lane & 7)) * 8;
  const int co1 = (((lane >> 4) + 4) ^ (lane & 7)) * 8;
  const int raA = (wr * 128 + (lane & 15)) * 64;
  const int raB = (wc * 64 + (lane & 15)) * 64;

  const int nk = K >> 6;

#pragma unroll
  for (int c = 0; c < 4; ++c) {
    gload_lds16(gA + (size_t)(c * 64) * K, &As[0][c * 4096 + dwave]);
    gload_lds16(gB + (size_t)(c * 64) * K, &Bs[0][c * 4096 + dwave]);
  }
  asm volatile("s_waitcnt vmcnt(0)" ::: "memory");
  __builtin_amdgcn_s_barrier();
  __builtin_amdgcn_sched_barrier(0);

#pragma unroll 2
  for (int t = 0; t < nk; ++t) {
    const int cb = t & 1;
    const int sb = cb ^ 1;
    const u16* Acur = &As[cb][0];
    const u16* Bcur = &Bs[cb][0];
    const bool stg = (t + 1 < nk);
    const size_t kto = (size_t)(t + 1) * 64;

    // ---------------- phase 0 ----------------
    asm volatile("s_waitcnt vmcnt(2)" ::: "memory");
    __builtin_amdgcn_s_barrier();
    bf16x8 bf[4][2];
#pragma unroll
    for (int n = 0; n < 4; ++n) {
      const int ro = raB + n * 16 * 64;
      bf[n][0] = *(const bf16x8*)&Bcur[ro + co0];
      bf[n][1] = *(const bf16x8*)&Bcur[ro + co1];
    }
    bf16x8 af[2][2];
#pragma unroll
    for (int mm = 0; mm < 2; ++mm) {
      const int ro = raA + (mm * 16) * 64;
      af[mm][0] = *(const bf16x8*)&Acur[ro + co0];
      af[mm][1] = *(const bf16x8*)&Acur[ro + co1];
    }
    if (stg) {
      gload_lds16(gB + kto, &Bs[sb][dwave]);
      gload_lds16(gB + (size_t)64 * K + kto, &Bs[sb][4096 + dwave]);
    }
    asm volatile("s_waitcnt lgkmcnt(0)" ::: "memory");
    __builtin_amdgcn_sched_barrier(0);
    __builtin_amdgcn_s_setprio(1);
#pragma unroll
    for (int mm = 0; mm < 2; ++mm)
#pragma unroll
      for (int n = 0; n < 4; ++n) {
        acc[mm][n] = __builtin_amdgcn_mfma_f32_16x16x32_bf16(af[mm][0], bf[n][0], acc[mm][n], 0, 0, 0);
        acc[mm][n] = __builtin_amdgcn_mfma_f32_16x16x32_bf16(af[mm][1], bf[n][1], acc[mm][n], 0, 0, 0);
      }
    __builtin_amdgcn_s_setprio(0);

    // ---------------- phase 1 ----------------
    __builtin_amdgcn_s_barrier();
#pragma unroll
    for (int mm = 0; mm < 2; ++mm) {
      const int ro = raA + (32 + mm * 16) * 64;
      af[mm][0] = *(const bf16x8*)&Acur[ro + co0];
      af[mm][1] = *(const bf16x8*)&Acur[ro + co1];
    }
    if (stg) {
      gload_lds16(gB + (size_t)128 * K + kto, &Bs[sb][2 * 4096 + dwave]);
      gload_lds16(gB + (size_t)192 * K + kto, &Bs[sb][3 * 4096 + dwave]);
    }
    asm volatile("s_waitcnt lgkmcnt(0)" ::: "memory");
    __builtin_amdgcn_sched_barrier(0);
    __builtin_amdgcn_s_setprio(1);
#pragma unroll
    for (int mm = 0; mm < 2; ++mm)
#pragma unroll
      for (int n = 0; n < 4; ++n) {
        acc[2 + mm][n] = __builtin_amdgcn_mfma_f32_16x16x32_bf16(af[mm][0], bf[n][0], acc[2 + mm][n], 0, 0, 0);
        acc[2 + mm][n] = __builtin_amdgcn_mfma_f32_16x16x32_bf16(af[mm][1], bf[n][1], acc[2 + mm][n], 0, 0, 0);
      }
    __builtin_amdgcn_s_setprio(0);

    // ---------------- phase 2 ----------------
    if (stg) {
      asm volatile("s_waitcnt vmcnt(4)" ::: "memory");
    } else {
      asm volatile("s_waitcnt vmcnt(0)" ::: "memory");
    }
    __builtin_amdgcn_s_barrier();
#pragma unroll
    for (int mm = 0; mm < 2; ++mm) {
      const int ro = raA + (64 + mm * 16) * 64;
      af[mm][0] = *(const bf16x8*)&Acur[ro + co0];
      af[mm][1] = *(const bf16x8*)&Acur[ro + co1];
    }
    if (stg) {
      gload_lds16(gA + kto, &As[sb][dwave]);
      gload_lds16(gA + (size_t)128 * K + kto, &As[sb][2 * 4096 + dwave]);
    }
    asm volatile("s_waitcnt lgkmcnt(0)" ::: "memory");
    __builtin_amdgcn_sched_barrier(0);
    __builtin_amdgcn_s_setprio(1);
#pragma unroll
    for (int mm = 0; mm < 2; ++mm)
#pragma unroll
      for (int n = 0; n < 4; ++n) {
        acc[4 + mm][n] = __builtin_amdgcn_mfma_f32_16x16x32_bf16(af[mm][0], bf[n][0], acc[4 + mm][n], 0, 0, 0);
        acc[4 + mm][n] = __builtin_amdgcn_mfma_f32_16x16x32_bf16(af[mm][1], bf[n][1], acc[4 + mm][n], 0, 0, 0);
      }
    __builtin_amdgcn_s_setprio(0);

    // ---------------- phase 3 ----------------
    __builtin_amdgcn_s_barrier();
#pragma unroll
    for (int mm = 0; mm < 2; ++mm) {
      const int ro = raA + (96 + mm * 16) * 64;
      af[mm][0] = *(const bf16x8*)&Acur[ro + co0];
      af[mm][1] = *(const bf16x8*)&Acur[ro + co1];
    }
    if (stg) {
      gload_lds16(gA + (size_t)64 * K + kto, &As[sb][4096 + dwave]);
      gload_lds16(gA + (size_t)192 * K + kto, &As[sb][3 * 4096 + dwave]);
    }
    asm volatile("s_waitcnt lgkmcnt(0)" ::: "memory");
    __builtin_amdgcn_sched_barrier(0);
    __builtin_amdgcn_s_setprio(1);
#pragma unroll
    for (int mm = 0; mm < 2; ++mm)
#pragma unroll
      for (int n = 0; n < 4; ++n) {
        acc[6 + mm][n] = __builtin_amdgcn_mfma_f32_16x16x32_bf16(af[mm][0], bf[n][0], acc[6 + mm][n], 0, 0, 0);
        acc[6 + mm][n] = __builtin_amdgcn_mfma_f32_16x16x32_bf16(af[mm][1], bf[n][1], acc[6 + mm][n], 0, 0, 0);
      }
    __builtin_amdgcn_s_setprio(0);
    __builtin_amdgcn_sched_barrier(0);
  }

  const int crow = m0 + wr * 128 + ((lane >> 4) << 2);
  const int ccol = n0 + wc * 64 + (lane & 15);
#pragma unroll
  for (int m = 0; m < 8; ++m)
#pragma unroll
    for (int n = 0; n < 4; ++n)
#pragma unroll
      for (int j = 0; j < 4; ++j)
        __builtin_nontemporal_store(acc[m][n][j],
            &C[(size_t)(crow + m * 16 + j) * N + ccol + n * 16]);
}

// ---------------------------------------------------------------------------
// 128x128 pipelined layer GEMM — R12/R14-benched drain-after-MFMA structure
// (reverted from R16 fine-phase: thin 8-MFMA phases don't amortize).
// EPI 0: bf16 partial store to (u16*)C0 + blockIdx.z * (2048*1024)
// EPI 1: QKV head-major bf16 from concat [3072][1024] weights
// EPI 2: bf16 gelu(acc + bias[col])
// ---------------------------------------------------------------------------
template <int EPI>
__global__ __launch_bounds__(256, 2) void gemm128p(
    const u16* __restrict__ A, const u16* __restrict__ Bt,
    void* __restrict__ C0, void* __restrict__ C1, void* __restrict__ C2,
    const float* __restrict__ bias, int N, int K)
{
  __shared__ u16 As[2][128 * 64];
  __shared__ u16 Bs[2][128 * 64];
  const int tid = threadIdx.x;
  const int lane = tid & 63;
  const int wid = tid >> 6;
  const int wr = wid >> 1;
  const int wc = wid & 1;

  const int T = (int)gridDim.x;
  const int bid = (int)blockIdx.x;
  const int q8 = T >> 3, r8 = T & 7;
  const int xcd = bid & 7, base = bid >> 3;
  const int swz = (xcd < r8 ? xcd * (q8 + 1) : r8 * (q8 + 1) + (xcd - r8) * q8) + base;
  const int m0 = (swz & 15) * 128;
  const int n0 = (swz >> 4) * 128;

  const int kchunk = K / (int)gridDim.z;
  const int kbeg = (int)blockIdx.z * kchunk;
  const int nk = kchunk >> 6;

  f32x4 acc[4][4] = {};

  const int srow = tid >> 3;
  const int sgr = (tid & 7) ^ (srow & 7);
  const u16* gA = A + (size_t)(m0 + srow) * K + kbeg + sgr * 8;
  const u16* gB = Bt + (size_t)(n0 + srow) * K + kbeg + sgr * 8;
  const int dwave = wid * 512;

  const int co0 = (((lane >> 4)) ^ (lane & 7)) * 8;
  const int co1 = (((lane >> 4) + 4) ^ (lane & 7)) * 8;
  const int raA = (wr * 64 + (lane & 15)) * 64;
  const int raB = (wc * 64 + (lane & 15)) * 64;

#pragma unroll
  for (int c = 0; c < 4; ++c) {
    gload_lds16(gA + (size_t)(c * 32) * K, &As[0][c * 2048 + dwave]);
    gload_lds16(gB + (size_t)(c * 32) * K, &Bs[0][c * 2048 + dwave]);
  }
#pragma unroll
  for (int c = 0; c < 4; ++c) {
    gload_lds16(gA + (size_t)(c * 32) * K + 64, &As[1][c * 2048 + dwave]);
    gload_lds16(gB + (size_t)(c * 32) * K + 64, &Bs[1][c * 2048 + dwave]);
  }
  asm volatile("s_waitcnt vmcnt(8)" ::: "memory");
  __builtin_amdgcn_s_barrier();
  __builtin_amdgcn_sched_barrier(0);

#pragma unroll 2
  for (int t = 0; t < nk; ++t) {
    const int cb = t & 1;
    const u16* Acur = &As[cb][0];
    const u16* Bcur = &Bs[cb][0];

    bf16x8 bf[4][2];
#pragma unroll
    for (int n = 0; n < 4; ++n) {
      const int ro = raB + n * 16 * 64;
      bf[n][0] = *(const bf16x8*)&Bcur[ro + co0];
      bf[n][1] = *(const bf16x8*)&Bcur[ro + co1];
    }
    bf16x8 af01[2][2];
#pragma unroll
    for (int p = 0; p < 2; ++p) {
      const int ro = raA + p * 16 * 64;
      af01[p][0] = *(const bf16x8*)&Acur[ro + co0];
      af01[p][1] = *(const bf16x8*)&Acur[ro + co1];
    }
    __builtin_amdgcn_s_setprio(1);
#pragma unroll
    for (int p = 0; p < 2; ++p)
#pragma unroll
      for (int n = 0; n < 4; ++n) {
        acc[p][n] = __builtin_amdgcn_mfma_f32_16x16x32_bf16(af01[p][0], bf[n][0], acc[p][n], 0, 0, 0);
        acc[p][n] = __builtin_amdgcn_mfma_f32_16x16x32_bf16(af01[p][1], bf[n][1], acc[p][n], 0, 0, 0);
      }
    __builtin_amdgcn_s_setprio(0);
    bf16x8 af23[2][2];
#pragma unroll
    for (int p = 0; p < 2; ++p) {
      const int ro = raA + (p + 2) * 16 * 64;
      af23[p][0] = *(const bf16x8*)&Acur[ro + co0];
      af23[p][1] = *(const bf16x8*)&Acur[ro + co1];
    }
    asm volatile("s_waitcnt lgkmcnt(0)" ::: "memory");
    __builtin_amdgcn_s_barrier();          // (1) all reads of buf[cb] retired
    if (t + 2 < nk) {
      const size_t kto = (size_t)(t + 2) * 64;
#pragma unroll
      for (int c = 0; c < 4; ++c) {
        gload_lds16(gA + (size_t)(c * 32) * K + kto, &As[cb][c * 2048 + dwave]);
        gload_lds16(gB + (size_t)(c * 32) * K + kto, &Bs[cb][c * 2048 + dwave]);
      }
    }
    __builtin_amdgcn_s_setprio(1);
#pragma unroll
    for (int p = 0; p < 2; ++p)
#pragma unroll
      for (int n = 0; n < 4; ++n) {
        acc[p + 2][n] = __builtin_amdgcn_mfma_f32_16x16x32_bf16(af23[p][0], bf[n][0], acc[p + 2][n], 0, 0, 0);
        acc[p + 2][n] = __builtin_amdgcn_mfma_f32_16x16x32_bf16(af23[p][1], bf[n][1], acc[p + 2][n], 0, 0, 0);
      }
    __builtin_amdgcn_s_setprio(0);
    if (t + 2 < nk) {
      asm volatile("s_waitcnt vmcnt(8)" ::: "memory");
    } else if (t + 1 < nk) {
      asm volatile("s_waitcnt vmcnt(0)" ::: "memory");
    }
    __builtin_amdgcn_s_barrier();          // (2) publish buf[cb^1]
    __builtin_amdgcn_sched_barrier(0);
  }

  const int z = (int)blockIdx.z;
#pragma unroll
  for (int m = 0; m < 4; ++m) {
    const int rowb = m0 + wr * 64 + m * 16 + ((lane >> 4) << 2);
#pragma unroll
    for (int n = 0; n < 4; ++n) {
      const int col = n0 + wc * 64 + n * 16 + (lane & 15);
#pragma unroll
      for (int j = 0; j < 4; ++j) {
        const int r = rowb + j;
        float v = acc[m][n][j];
        if (EPI == 0) {
          u16* outp = (u16*)C0 + (size_t)z * (2048u * 1024u);
          outp[(size_t)r * N + col] = f2b(v);
        } else if (EPI == 1) {
          const int which = col >> 10;
          const int ci = col & 1023;
          u16* outp = (u16*)((which == 0) ? C0 : (which == 1) ? C1 : C2);
          outp[((size_t)(ci >> 6) * SEQ + r) * 64 + (ci & 63)] = f2b(v);
        } else {
          float xx = v + bias[col];
          float ge = 0.5f * xx * (1.0f + erff(xx * 0.70710678118654752f));
          ((u16*)C0)[(size_t)r * N + col] = f2b(ge);
        }
      }
    }
  }
}

// ---------------------------------------------------------------------------
// Fallback logits GEMM (fp32 B, BK=32) if emb_bf16 doesn't fit ws.
// ---------------------------------------------------------------------------
__global__ __launch_bounds__(256) void gemm_f32b(
    const u16* __restrict__ A, const float* __restrict__ Bt,
    float* __restrict__ C0, int N, int K)
{
  __shared__ u16 As[128 * 32];
  __shared__ u16 Bs[128 * 32];
  const int tid = threadIdx.x;
  const int lane = tid & 63;
  const int w = tid >> 6;
  const int wr = w >> 1;
  const int wc = w & 1;

  const int T = (int)gridDim.x;
  const int bid = (int)blockIdx.x;
  const int q8 = T >> 3, r8 = T & 7;
  const int xcd = bid & 7, base = bid >> 3;
  int swz = (xcd < r8 ? xcd * (q8 + 1) : r8 * (q8 + 1) + (xcd - r8) * q8) + base;
  const int m0 = (swz & 15) * 128;
  const int n0 = (swz >> 4) * 128;

  f32x4 acc[4][4] = {};
  const u16* ga0 = A + (size_t)(m0 + w * 32 + (lane >> 2)) * K + (lane & 3) * 8;
  u16* la = &As[(w * 32) * 32];
  const float* gb32 = Bt + (size_t)(n0 + (tid >> 1)) * K + (tid & 1) * 16;
  u16* lbw = &Bs[(tid >> 1) * 32 + (tid & 1) * 16];

  for (int kt = 0; kt < K; kt += 32) {
    __syncthreads();
    gload_lds16(ga0 + kt, la);
    gload_lds16(ga0 + kt + 16 * K, la + 16 * 32);
    {
      const float4 f0 = *(const float4*)(gb32 + kt);
      const float4 f1 = *(const float4*)(gb32 + kt + 4);
      const float4 f2 = *(const float4*)(gb32 + kt + 8);
      const float4 f3 = *(const float4*)(gb32 + kt + 12);
      union { bf16x8 b; u16x8 u; } lo, hi;
      lo.b[0] = (__bf16)f0.x; lo.b[1] = (__bf16)f0.y;
      lo.b[2] = (__bf16)f0.z; lo.b[3] = (__bf16)f0.w;
      lo.b[4] = (__bf16)f1.x; lo.b[5] = (__bf16)f1.y;
      lo.b[6] = (__bf16)f1.z; lo.b[7] = (__bf16)f1.w;
      hi.b[0] = (__bf16)f2.x; hi.b[1] = (__bf16)f2.y;
      hi.b[2] = (__bf16)f2.z; hi.b[3] = (__bf16)f2.w;
      hi.b[4] = (__bf16)f3.x; hi.b[5] = (__bf16)f3.y;
      hi.b[6] = (__bf16)f3.z; hi.b[7] = (__bf16)f3.w;
      *(u16x8*)lbw = lo.u;
      *(u16x8*)(lbw + 8) = hi.u;
    }
    asm volatile("s_waitcnt vmcnt(0)" ::: "memory");
    __syncthreads();
    bf16x8 af[4], bfr[4];
#pragma unroll
    for (int m = 0; m < 4; ++m)
      af[m] = *(const bf16x8*)&As[(wr * 64 + m * 16 + (lane & 15)) * 32 + (lane >> 4) * 8];
#pragma unroll
    for (int n = 0; n < 4; ++n)
      bfr[n] = *(const bf16x8*)&Bs[(wc * 64 + n * 16 + (lane & 15)) * 32 + (lane >> 4) * 8];
#pragma unroll
    for (int m = 0; m < 4; ++m)
#pragma unroll
      for (int n = 0; n < 4; ++n)
        acc[m][n] = __builtin_amdgcn_mfma_f32_16x16x32_bf16(af[m], bfr[n], acc[m][n], 0, 0, 0);
  }

#pragma unroll
  for (int m = 0; m < 4; ++m) {
    const int rowb = m0 + wr * 64 + m * 16 + ((lane >> 4) << 2);
#pragma unroll
    for (int n = 0; n < 4; ++n) {
      const int col = n0 + wc * 64 + n * 16 + (lane & 15);
#pragma unroll
      for (int j = 0; j < 4; ++j)
        __builtin_nontemporal_store(acc[m][n][j],
            &C0[(size_t)(rowb + j) * N + col]);
    }
  }
}

// ---------------------------------------------------------------------------
// LayerNorm (plain): fp32 x[row][1024] -> bf16 h
// ---------------------------------------------------------------------------
__global__ __launch_bounds__(256) void ln_kernel(const float* __restrict__ x,
    const float* __restrict__ g, const float* __restrict__ b, u16* __restrict__ out)
{
  const int row = blockIdx.x;
  const int tid = threadIdx.x;
  const float4 v = ((const float4*)(x + (size_t)row * 1024))[tid];
  float s = v.x + v.y + v.z + v.w;
  float sq = v.x * v.x + v.y * v.y + v.z * v.z + v.w * v.w;
#pragma unroll
  for (int o = 1; o < 64; o <<= 1) { s += __shfl_xor(s, o); sq += __shfl_xor(sq, o); }
  __shared__ float ss[4], ssq[4];
  if ((tid & 63) == 0) { ss[tid >> 6] = s; ssq[tid >> 6] = sq; }
  __syncthreads();
  s = ss[0] + ss[1] + ss[2] + ss[3];
  sq = ssq[0] + ssq[1] + ssq[2] + ssq[3];
  const float mean = s * (1.0f / 1024.0f);
  const float var = sq * (1.0f / 1024.0f) - mean * mean;
  const float rstd = rsqrtf(var + 1e-5f);
  const int c = tid * 4;
  u16* o4 = out + (size_t)row * 1024 + c;
  const float4 gg = ((const float4*)g)[tid];
  const float4 bb = ((const float4*)b)[tid];
  o4[0] = f2b((v.x - mean) * rstd * gg.x + bb.x);
  o4[1] = f2b((v.y - mean) * rstd * gg.y + bb.y);
  o4[2] = f2b((v.z - mean) * rstd * gg.z + bb.z);
  o4[3] = f2b((v.w - mean) * rstd * gg.w + bb.w);
}

// ---------------------------------------------------------------------------
// Fused residual + LayerNorm, 4 bf16 split-K partials.
// ---------------------------------------------------------------------------
__global__ __launch_bounds__(256) void ln_res4(float* __restrict__ x,
    const u16* __restrict__ P, const float* __restrict__ bias,
    const float* __restrict__ g, const float* __restrict__ b,
    u16* __restrict__ out)
{
  const int row = blockIdx.x;
  const int tid = threadIdx.x;
  const size_t off = (size_t)row * 1024;
  float4 v = ((const float4*)(x + off))[tid];
#pragma unroll
  for (int j = 0; j < 4; ++j) {
    const u16x4 a = *(const u16x4*)(P + (size_t)j * 2048 * 1024 + off + tid * 4);
    v.x += b2f(a[0]); v.y += b2f(a[1]); v.z += b2f(a[2]); v.w += b2f(a[3]);
  }
  if (bias != nullptr) {
    const float4 bi = ((const float4*)bias)[tid];
    v.x += bi.x; v.y += bi.y; v.z += bi.z; v.w += bi.w;
  }
  ((float4*)(x + off))[tid] = v;
  float s = v.x + v.y + v.z + v.w;
  float sq = v.x * v.x + v.y * v.y + v.z * v.z + v.w * v.w;
#pragma unroll
  for (int o = 1; o < 64; o <<= 1) { s += __shfl_xor(s, o); sq += __shfl_xor(sq, o); }
  __shared__ float ss[4], ssq[4];
  if ((tid & 63) == 0) { ss[tid >> 6] = s; ssq[tid >> 6] = sq; }
  __syncthreads();
  s = ss[0] + ss[1] + ss[2] + ss[3];
  sq = ssq[0] + ssq[1] + ssq[2] + ssq[3];
  const float mean = s * (1.0f / 1024.0f);
  const float var = sq * (1.0f / 1024.0f) - mean * mean;
  const float rstd = rsqrtf(var + 1e-5f);
  const int c = tid * 4;
  u16* o4 = out + off + c;
  const float4 gg = ((const float4*)g)[tid];
  const float4 bb = ((const float4*)b)[tid];
  o4[0] = f2b((v.x - mean) * rstd * gg.x + bb.x);
  o4[1] = f2b((v.y - mean) * rstd * gg.y + bb.y);
  o4[2] = f2b((v.z - mean) * rstd * gg.z + bb.z);
  o4[3] = f2b((v.w - mean) * rstd * gg.w + bb.w);
}

// ---------------------------------------------------------------------------
// Embedding gather: x[s][d] = emb_fp32[ids[s]][d]
// ---------------------------------------------------------------------------
__global__ __launch_bounds__(256) void gather_kernel(const int* __restrict__ ids,
    const float* __restrict__ emb, float* __restrict__ x)
{
  const int srow = blockIdx.x;
  const int tid = threadIdx.x;
  const int id = ids[srow];
  ((float4*)(x + (size_t)srow * 1024))[tid] =
      ((const float4*)(emb + (size_t)id * 1024))[tid];
}

// ---------------------------------------------------------------------------
// Flash attention w/ ALiBi + causal (R11 config: 512 blocks x 128 threads).
// ---------------------------------------------------------------------------
__global__ __launch_bounds__(128) void attn_kernel(
    const u16* __restrict__ q, const u16* __restrict__ k, const u16* __restrict__ v,
    const float* __restrict__ slopes, u16* __restrict__ out)
{
  const int bid = (int)blockIdx.x;
  const int h = bid & 15;
  const int qi = 31 - (bid >> 4);
  const int q0 = qi * 64;
  const int tid = threadIdx.x;
  const int lane = tid & 63;
  const int w = tid >> 6;
  const float slope = slopes[h];

  __shared__ u16 Ks[2][64 * 32];
  __shared__ u16 Vt[64][72];
  __shared__ u16 Pl[2][32][72];

  const u16* qb = q + ((size_t)h * SEQ + q0 + w * 32) * 64;
  bf16x8 qf[2][2];
#pragma unroll
  for (int m = 0; m < 2; ++m)
#pragma unroll
    for (int kk = 0; kk < 2; ++kk)
      qf[m][kk] = *(const bf16x8*)(qb + (m * 16 + (lane & 15)) * 64 + kk * 32 + (lane >> 4) * 8);

  f32x4 o_acc[2][4] = {};
  float mrun[2][4], lrun[2][4];
#pragma unroll
  for (int m = 0; m < 2; ++m)
#pragma unroll
    for (int j = 0; j < 4; ++j) { mrun[m][j] = -1e30f; lrun[m][j] = 0.0f; }

  const int ntiles = qi + 1;
  const int wmaxrow = q0 + w * 32 + 31;

  const int ksl = (lane & 3) ^ ((lane >> 2) & 3);
  const u16* gk0 = k + ((size_t)h * SEQ + (lane >> 2)) * 64 + w * 32 + ksl * 8;
  u16* lk = &Ks[w][0];
  const u16* gv0 = v + ((size_t)h * SEQ + lane) * 64 + w * 32;
  const int krd = ((lane >> 4) ^ (lane & 3)) * 8;

  for (int t = 0; t < ntiles; ++t) {
    const int j0 = t << 6;
    __syncthreads();
#pragma unroll
    for (int r = 0; r < 4; ++r)
      gload_lds16(gk0 + (size_t)(j0 + r * 16) * 64, lk + r * 16 * 32);
    {
      const u16* gvp = gv0 + (size_t)j0 * 64;
      u16x8 v0 = *(const u16x8*)gvp;
      u16x8 v1 = *(const u16x8*)(gvp + 8);
      u16x8 v2 = *(const u16x8*)(gvp + 16);
      u16x8 v3 = *(const u16x8*)(gvp + 24);
      const int d0 = w * 32;
#pragma unroll
      for (int i = 0; i < 8; ++i) Vt[d0 + i][lane] = v0[i];
#pragma unroll
      for (int i = 0; i < 8; ++i) Vt[d0 + 8 + i][lane] = v1[i];
#pragma unroll
      for (int i = 0; i < 8; ++i) Vt[d0 + 16 + i][lane] = v2[i];
#pragma unroll
      for (int i = 0; i < 8; ++i) Vt[d0 + 24 + i][lane] = v3[i];
    }
    asm volatile("s_waitcnt vmcnt(0)" ::: "memory");
    __syncthreads();

    if (wmaxrow >= j0) {
      f32x4 s[2][4] = {};
      __builtin_amdgcn_s_setprio(1);
#pragma unroll
      for (int kk = 0; kk < 2; ++kk) {
        bf16x8 kf[4];
#pragma unroll
        for (int n = 0; n < 4; ++n)
          kf[n] = *(const bf16x8*)&Ks[kk][(n * 16 + (lane & 15)) * 32 + krd];
#pragma unroll
        for (int m = 0; m < 2; ++m)
#pragma unroll
          for (int n = 0; n < 4; ++n)
            s[m][n] = __builtin_amdgcn_mfma_f32_16x16x32_bf16(qf[m][kk], kf[n], s[m][n], 0, 0, 0);
      }
      __builtin_amdgcn_s_setprio(0);
      const int rq = q0 + w * 32 + ((lane >> 4) << 2);
      const int ck = j0 + (lane & 15);
#pragma unroll
      for (int m = 0; m < 2; ++m) {
#pragma unroll
        for (int j = 0; j < 4; ++j) {
          const int qi2 = rq + m * 16 + j;
          float mx = -1e30f;
#pragma unroll
          for (int n = 0; n < 4; ++n) {
            const int kj = ck + n * 16;
            float val = s[m][n][j] * 0.125f - slope * (float)(kj - qi2);
            val = (kj <= qi2) ? val : -1e30f;
            s[m][n][j] = val;
            mx = fmaxf(mx, val);
          }
#pragma unroll
          for (int o = 1; o < 16; o <<= 1) mx = fmaxf(mx, __shfl_xor(mx, o));
          const float mnew = fmaxf(mrun[m][j], mx);
          const float alpha = __expf(mrun[m][j] - mnew);
          mrun[m][j] = mnew;
          float rs = 0.0f;
          const int prow = m * 16 + ((lane >> 4) << 2) + j;
#pragma unroll
          for (int n = 0; n < 4; ++n) {
            const float p = __expf(s[m][n][j] - mnew);
            rs += p;
            Pl[w][prow][n * 16 + (lane & 15)] = f2b(p);
          }
#pragma unroll
          for (int o = 1; o < 16; o <<= 1) rs += __shfl_xor(rs, o);
          lrun[m][j] = lrun[m][j] * alpha + rs;
#pragma unroll
          for (int n = 0; n < 4; ++n) o_acc[m][n][j] *= alpha;
        }
      }
      __builtin_amdgcn_s_setprio(1);
#pragma unroll
      for (int kk = 0; kk < 2; ++kk) {
        bf16x8 pf[2], vf[4];
#pragma unroll
        for (int m = 0; m < 2; ++m)
          pf[m] = *(const bf16x8*)&Pl[w][m * 16 + (lane & 15)][kk * 32 + (lane >> 4) * 8];
#pragma unroll
        for (int n = 0; n < 4; ++n)
          vf[n] = *(const bf16x8*)&Vt[n * 16 + (lane & 15)][kk * 32 + (lane >> 4) * 8];
#pragma unroll
        for (int m = 0; m < 2; ++m)
#pragma unroll
          for (int n = 0; n < 4; ++n)
            o_acc[m][n] = __builtin_amdgcn_mfma_f32_16x16x32_bf16(pf[m], vf[n], o_acc[m][n], 0, 0, 0);
      }
      __builtin_amdgcn_s_setprio(0);
    }
  }

#pragma unroll
  for (int m = 0; m < 2; ++m) {
    const int sbase = q0 + w * 32 + m * 16 + ((lane >> 4) << 2);
#pragma unroll
    for (int n = 0; n < 4; ++n) {
      const int d = h * 64 + n * 16 + (lane & 15);
#pragma unroll
      for (int j = 0; j < 4; ++j)
        out[(size_t)(sbase + j) * 1024 + d] = f2b(o_acc[m][n][j] / lrun[m][j]);
    }
  }
}

// ---------------------------------------------------------------------------
extern "C" void kernel_launch(void* const* d_in, const int* in_sizes, int n_in,
                              void* d_out, int out_size, void* d_ws, size_t ws_size,
                              hipStream_t stream)
{
  (void)in_sizes; (void)n_in; (void)out_size;
  const int* ids = (const int*)d_in[0];
  const float* emb = (const float*)d_in[1];
  const float* slopes = (const float*)d_in[2];
  const float* Wq = (const float*)d_in[3];
  const float* Wk = (const float*)d_in[4];
  const float* Wv = (const float*)d_in[5];
  const float* Wo = (const float*)d_in[6];
  const float* W1 = (const float*)d_in[7];
  const float* b1 = (const float*)d_in[8];
  const float* W2 = (const float*)d_in[9];
  const float* b2 = (const float*)d_in[10];
  const float* g1 = (const float*)d_in[11];
  const float* be1 = (const float*)d_in[12];
  const float* g2 = (const float*)d_in[13];
  const float* be2 = (const float*)d_in[14];
  const float* gf = (const float*)d_in[15];
  const float* bfin = (const float*)d_in[16];

  char* ob = (char*)d_out;
  float* x    = (float*)ob;                          // 8 MB fp32 residual
  u16* qb     = (u16*)(ob + (size_t)( 8u << 20));    // 4 MB
  u16* kb     = (u16*)(ob + (size_t)(12u << 20));    // 4 MB
  u16* vb     = (u16*)(ob + (size_t)(16u << 20));    // 4 MB
  u16* attn   = (u16*)(ob + (size_t)(20u << 20));    // 4 MB
  u16* ff     = (u16*)(ob + (size_t)(24u << 20));    // 16 MB
  u16* Wqkv_b = (u16*)(ob + (size_t)( 40u << 20));   // 24 MB  [4][3072][1024]
  u16* Wo_b   = (u16*)(ob + (size_t)( 64u << 20));   // 8 MB
  u16* W1_b   = (u16*)(ob + (size_t)( 72u << 20));   // 32 MB
  u16* W2_b   = (u16*)(ob + (size_t)(104u << 20));   // 32 MB
  u16* P      = (u16*)(ob + (size_t)(136u << 20));   // 16 MB: 4 bf16 partials
  u16* h      = (u16*)d_ws;                          // 4 MB
  const size_t emb_b_need = (size_t)(4u << 20) + (size_t)32000 * 1024 * 2;
  const bool emb_fits = ws_size >= emb_b_need;
  u16* emb_b = (u16*)((char*)d_ws + (4u << 20));
  float* logits = (float*)d_out;

  {
    CvtArgs a;
    const u32 wsz = 4 * 1024 * 1024 / 8;
    const u32 fsz = 16 * 1024 * 1024 / 8;
    const u32 esz = 32000 * 1024 / 8;
    a.src[0] = Wq; a.dst[0] = Wqkv_b;
    a.src[1] = Wk; a.dst[1] = Wqkv_b + 1024 * 1024;
    a.src[2] = Wv; a.dst[2] = Wqkv_b + 2 * 1024 * 1024;
    a.src[3] = Wo; a.dst[3] = Wo_b;
    a.src[4] = W1; a.dst[4] = W1_b;
    a.src[5] = W2; a.dst[5] = W2_b;
    a.src[6] = emb; a.dst[6] = emb_b;
    a.beg[0] = 0;
    a.beg[1] = wsz;      a.beg[2] = 2 * wsz;  a.beg[3] = 3 * wsz;
    a.beg[4] = 4 * wsz;  a.beg[5] = 4 * wsz + fsz;  a.beg[6] = 4 * wsz + 2 * fsz;
    a.beg[7] = a.beg[6] + esz;
    a.total = emb_fits ? a.beg[7] : a.beg[6];
    cvt_all<<<2048, 256, 0, stream>>>(a);
  }

  gather_kernel<<<2048, 256, 0, stream>>>(ids, emb, x);
  ln_kernel<<<2048, 256, 0, stream>>>(x, g1, be1, h);

  for (int l = 0; l < 4; ++l) {
    const size_t wqkv = (size_t)l * 3072 * 1024;
    const size_t wo = (size_t)l * 1024 * 1024;
    const size_t wf = (size_t)l * 4096 * 1024;
    gemm128p<1><<<dim3(384, 1, 1), 256, 0, stream>>>(h, Wqkv_b + wqkv,
        qb, kb, vb, nullptr, 3072, 1024);
    attn_kernel<<<dim3(512, 1, 1), 128, 0, stream>>>(qb, kb, vb, slopes, attn);
    gemm128p<0><<<dim3(128, 1, 4), 256, 0, stream>>>(attn, Wo_b + wo,
        P, nullptr, nullptr, nullptr, 1024, 1024);
    ln_res4<<<2048, 256, 0, stream>>>(x, P, nullptr,
        g2 + l * 1024, be2 + l * 1024, h);
    gemm128p<2><<<dim3(512, 1, 1), 256, 0, stream>>>(h, W1_b + wf,
        ff, nullptr, nullptr, b1 + l * 4096, 4096, 1024);
    gemm128p<0><<<dim3(128, 1, 4), 256, 0, stream>>>(ff, W2_b + wf,
        P, nullptr, nullptr, nullptr, 1024, 4096);
    if (l < 3) {
      ln_res4<<<2048, 256, 0, stream>>>(x, P, b2 + l * 1024,
          g1 + (l + 1) * 1024, be1 + (l + 1) * 1024, h);
    } else {
      ln_res4<<<2048, 256, 0, stream>>>(x, P, b2 + l * 1024, gf, bfin, h);
    }
  }

  if (emb_fits) {
    gemm256<<<dim3(1000, 1, 1), 512, 0, stream>>>(h, emb_b, logits, 32000, 1024);
  } else {
    gemm_f32b<<<dim3(4000, 1, 1), 256, 0, stream>>>(h, emb, logits, 32000, 1024);
  }
}

// Round 18
// 1134.246 us; speedup vs baseline: 1.0208x; 1.0082x over previous
//
#include <hip/hip_runtime.h>
#include <hip/hip_bf16.h>

typedef unsigned int u32;
typedef unsigned short u16;
typedef __attribute__((ext_vector_type(8))) __bf16 bf16x8;
typedef __attribute__((ext_vector_type(8))) unsigned short u16x8;
typedef __attribute__((ext_vector_type(4))) unsigned short u16x4;
typedef __attribute__((ext_vector_type(4))) float f32x4;

#define SEQ 2048

__device__ __forceinline__ float b2f(u16 u) {
  union { u32 i; float f; } x; x.i = ((u32)u) << 16; return x.f;
}
__device__ __forceinline__ u16 f2b(float f) {
  u32 u = __float_as_uint(f);
  u = (u + 0x7fffu + ((u >> 16) & 1u)) >> 16;
  return (u16)u;
}
__device__ __forceinline__ void gload_lds16(const void* g, void* l) {
  __builtin_amdgcn_global_load_lds((const __attribute__((address_space(1))) u32*)g,
                                   (__attribute__((address_space(3))) u32*)l, 16, 0, 0);
}

// ---------------------------------------------------------------------------
// Fused fp32 -> bf16 bulk convert. Segments 0-2 (Wq/Wk/Wv) are remapped into
// a concatenated [L][3072][1024] layout.
// ---------------------------------------------------------------------------
struct CvtArgs {
  const float* src[7];
  u16* dst[7];
  u32 beg[8];
  u32 total;
};

__global__ __launch_bounds__(256) void cvt_all(CvtArgs a)
{
  for (u32 i = blockIdx.x * 256 + threadIdx.x; i < a.total; i += gridDim.x * 256) {
    int s = 0;
#pragma unroll
    for (int k = 1; k < 7; ++k) s += (i >= a.beg[k]);
    const u32 li = i - a.beg[s];
    const float* in = a.src[s];
    const float4 f0 = ((const float4*)in)[(size_t)li * 2];
    const float4 f1 = ((const float4*)in)[(size_t)li * 2 + 1];
    union { bf16x8 b; u16x8 u; } r;
    r.b[0] = (__bf16)f0.x; r.b[1] = (__bf16)f0.y;
    r.b[2] = (__bf16)f0.z; r.b[3] = (__bf16)f0.w;
    r.b[4] = (__bf16)f1.x; r.b[5] = (__bf16)f1.y;
    r.b[6] = (__bf16)f1.z; r.b[7] = (__bf16)f1.w;
    u16* d;
    if (s < 3) {
      const u32 layer = li >> 17;
      const u32 rem = li & 131071u;
      d = a.dst[s] + ((size_t)layer * 393216u + rem) * 8;
    } else {
      d = a.dst[s] + (size_t)li * 8;
    }
    *(u16x8*)d = r.u;
  }
}

// ---------------------------------------------------------------------------
// 256x256 logits GEMM — R15-proven fine 4-phase schedule, plain stores.
// ---------------------------------------------------------------------------
__global__ __launch_bounds__(512, 2) void gemm256(
    const u16* __restrict__ A, const u16* __restrict__ Bt,
    float* __restrict__ C, int N, int K)
{
  __shared__ u16 As[2][256 * 64];
  __shared__ u16 Bs[2][256 * 64];
  const int tid = threadIdx.x;
  const int lane = tid & 63;
  const int wid = tid >> 6;
  const int wr = wid >> 2;
  const int wc = wid & 3;

  const int T = (int)gridDim.x;
  const int bid = (int)blockIdx.x;
  const int q8 = T >> 3, r8 = T & 7;
  const int xcd = bid & 7, base = bid >> 3;
  const int swz = (xcd < r8 ? xcd * (q8 + 1) : r8 * (q8 + 1) + (xcd - r8) * q8) + base;
  const int m0 = (swz & 7) * 256;
  const int n0 = (swz >> 3) * 256;

  f32x4 acc[8][4] = {};

  const int srow = tid >> 3;
  const int sgr = (tid & 7) ^ (srow & 7);
  const u16* gA = A + (size_t)(m0 + srow) * K + sgr * 8;
  const u16* gB = Bt + (size_t)(n0 + srow) * K + sgr * 8;
  const int dwave = wid * 512;

  const int co0 = (((lane >> 4)) ^ (lane & 7)) * 8;
  const int co1 = (((lane >> 4) + 4) ^ (lane & 7)) * 8;
  const int raA = (wr * 128 + (lane & 15)) * 64;
  const int raB = (wc * 64 + (lane & 15)) * 64;

  const int nk = K >> 6;

#pragma unroll
  for (int c = 0; c < 4; ++c) {
    gload_lds16(gA + (size_t)(c * 64) * K, &As[0][c * 4096 + dwave]);
    gload_lds16(gB + (size_t)(c * 64) * K, &Bs[0][c * 4096 + dwave]);
  }
  asm volatile("s_waitcnt vmcnt(0)" ::: "memory");
  __builtin_amdgcn_s_barrier();
  __builtin_amdgcn_sched_barrier(0);

#pragma unroll 2
  for (int t = 0; t < nk; ++t) {
    const int cb = t & 1;
    const int sb = cb ^ 1;
    const u16* Acur = &As[cb][0];
    const u16* Bcur = &Bs[cb][0];
    const bool stg = (t + 1 < nk);
    const size_t kto = (size_t)(t + 1) * 64;

    // ---------------- phase 0 ----------------
    asm volatile("s_waitcnt vmcnt(2)" ::: "memory");
    __builtin_amdgcn_s_barrier();
    bf16x8 bf[4][2];
#pragma unroll
    for (int n = 0; n < 4; ++n) {
      const int ro = raB + n * 16 * 64;
      bf[n][0] = *(const bf16x8*)&Bcur[ro + co0];
      bf[n][1] = *(const bf16x8*)&Bcur[ro + co1];
    }
    bf16x8 af[2][2];
#pragma unroll
    for (int mm = 0; mm < 2; ++mm) {
      const int ro = raA + (mm * 16) * 64;
      af[mm][0] = *(const bf16x8*)&Acur[ro + co0];
      af[mm][1] = *(const bf16x8*)&Acur[ro + co1];
    }
    if (stg) {
      gload_lds16(gB + kto, &Bs[sb][dwave]);
      gload_lds16(gB + (size_t)64 * K + kto, &Bs[sb][4096 + dwave]);
    }
    asm volatile("s_waitcnt lgkmcnt(0)" ::: "memory");
    __builtin_amdgcn_sched_barrier(0);
    __builtin_amdgcn_s_setprio(1);
#pragma unroll
    for (int mm = 0; mm < 2; ++mm)
#pragma unroll
      for (int n = 0; n < 4; ++n) {
        acc[mm][n] = __builtin_amdgcn_mfma_f32_16x16x32_bf16(af[mm][0], bf[n][0], acc[mm][n], 0, 0, 0);
        acc[mm][n] = __builtin_amdgcn_mfma_f32_16x16x32_bf16(af[mm][1], bf[n][1], acc[mm][n], 0, 0, 0);
      }
    __builtin_amdgcn_s_setprio(0);

    // ---------------- phase 1 ----------------
    __builtin_amdgcn_s_barrier();
#pragma unroll
    for (int mm = 0; mm < 2; ++mm) {
      const int ro = raA + (32 + mm * 16) * 64;
      af[mm][0] = *(const bf16x8*)&Acur[ro + co0];
      af[mm][1] = *(const bf16x8*)&Acur[ro + co1];
    }
    if (stg) {
      gload_lds16(gB + (size_t)128 * K + kto, &Bs[sb][2 * 4096 + dwave]);
      gload_lds16(gB + (size_t)192 * K + kto, &Bs[sb][3 * 4096 + dwave]);
    }
    asm volatile("s_waitcnt lgkmcnt(0)" ::: "memory");
    __builtin_amdgcn_sched_barrier(0);
    __builtin_amdgcn_s_setprio(1);
#pragma unroll
    for (int mm = 0; mm < 2; ++mm)
#pragma unroll
      for (int n = 0; n < 4; ++n) {
        acc[2 + mm][n] = __builtin_amdgcn_mfma_f32_16x16x32_bf16(af[mm][0], bf[n][0], acc[2 + mm][n], 0, 0, 0);
        acc[2 + mm][n] = __builtin_amdgcn_mfma_f32_16x16x32_bf16(af[mm][1], bf[n][1], acc[2 + mm][n], 0, 0, 0);
      }
    __builtin_amdgcn_s_setprio(0);

    // ---------------- phase 2 ----------------
    if (stg) {
      asm volatile("s_waitcnt vmcnt(4)" ::: "memory");
    } else {
      asm volatile("s_waitcnt vmcnt(0)" ::: "memory");
    }
    __builtin_amdgcn_s_barrier();
#pragma unroll
    for (int mm = 0; mm < 2; ++mm) {
      const int ro = raA + (64 + mm * 16) * 64;
      af[mm][0] = *(const bf16x8*)&Acur[ro + co0];
      af[mm][1] = *(const bf16x8*)&Acur[ro + co1];
    }
    if (stg) {
      gload_lds16(gA + kto, &As[sb][dwave]);
      gload_lds16(gA + (size_t)128 * K + kto, &As[sb][2 * 4096 + dwave]);
    }
    asm volatile("s_waitcnt lgkmcnt(0)" ::: "memory");
    __builtin_amdgcn_sched_barrier(0);
    __builtin_amdgcn_s_setprio(1);
#pragma unroll
    for (int mm = 0; mm < 2; ++mm)
#pragma unroll
      for (int n = 0; n < 4; ++n) {
        acc[4 + mm][n] = __builtin_amdgcn_mfma_f32_16x16x32_bf16(af[mm][0], bf[n][0], acc[4 + mm][n], 0, 0, 0);
        acc[4 + mm][n] = __builtin_amdgcn_mfma_f32_16x16x32_bf16(af[mm][1], bf[n][1], acc[4 + mm][n], 0, 0, 0);
      }
    __builtin_amdgcn_s_setprio(0);

    // ---------------- phase 3 ----------------
    __builtin_amdgcn_s_barrier();
#pragma unroll
    for (int mm = 0; mm < 2; ++mm) {
      const int ro = raA + (96 + mm * 16) * 64;
      af[mm][0] = *(const bf16x8*)&Acur[ro + co0];
      af[mm][1] = *(const bf16x8*)&Acur[ro + co1];
    }
    if (stg) {
      gload_lds16(gA + (size_t)64 * K + kto, &As[sb][4096 + dwave]);
      gload_lds16(gA + (size_t)192 * K + kto, &As[sb][3 * 4096 + dwave]);
    }
    asm volatile("s_waitcnt lgkmcnt(0)" ::: "memory");
    __builtin_amdgcn_sched_barrier(0);
    __builtin_amdgcn_s_setprio(1);
#pragma unroll
    for (int mm = 0; mm < 2; ++mm)
#pragma unroll
      for (int n = 0; n < 4; ++n) {
        acc[6 + mm][n] = __builtin_amdgcn_mfma_f32_16x16x32_bf16(af[mm][0], bf[n][0], acc[6 + mm][n], 0, 0, 0);
        acc[6 + mm][n] = __builtin_amdgcn_mfma_f32_16x16x32_bf16(af[mm][1], bf[n][1], acc[6 + mm][n], 0, 0, 0);
      }
    __builtin_amdgcn_s_setprio(0);
    __builtin_amdgcn_sched_barrier(0);
  }

  const int crow = m0 + wr * 128 + ((lane >> 4) << 2);
  const int ccol = n0 + wc * 64 + (lane & 15);
#pragma unroll
  for (int m = 0; m < 8; ++m)
#pragma unroll
    for (int n = 0; n < 4; ++n)
#pragma unroll
      for (int j = 0; j < 4; ++j)
        C[(size_t)(crow + m * 16 + j) * N + ccol + n * 16] = acc[m][n][j];
}

// ---------------------------------------------------------------------------
// 128x128 pipelined layer GEMM — R12/R14-benched drain-after-MFMA structure.
// EPI 0: bf16 partial store to (u16*)C0 + blockIdx.z * (2048*1024)
// EPI 1: QKV head-major bf16 from concat [3072][1024] weights
// EPI 2: bf16 gelu(acc + bias[col])
// ---------------------------------------------------------------------------
template <int EPI>
__global__ __launch_bounds__(256, 2) void gemm128p(
    const u16* __restrict__ A, const u16* __restrict__ Bt,
    void* __restrict__ C0, void* __restrict__ C1, void* __restrict__ C2,
    const float* __restrict__ bias, int N, int K)
{
  __shared__ u16 As[2][128 * 64];
  __shared__ u16 Bs[2][128 * 64];
  const int tid = threadIdx.x;
  const int lane = tid & 63;
  const int wid = tid >> 6;
  const int wr = wid >> 1;
  const int wc = wid & 1;

  const int T = (int)gridDim.x;
  const int bid = (int)blockIdx.x;
  const int q8 = T >> 3, r8 = T & 7;
  const int xcd = bid & 7, base = bid >> 3;
  const int swz = (xcd < r8 ? xcd * (q8 + 1) : r8 * (q8 + 1) + (xcd - r8) * q8) + base;
  const int m0 = (swz & 15) * 128;
  const int n0 = (swz >> 4) * 128;

  const int kchunk = K / (int)gridDim.z;
  const int kbeg = (int)blockIdx.z * kchunk;
  const int nk = kchunk >> 6;

  f32x4 acc[4][4] = {};

  const int srow = tid >> 3;
  const int sgr = (tid & 7) ^ (srow & 7);
  const u16* gA = A + (size_t)(m0 + srow) * K + kbeg + sgr * 8;
  const u16* gB = Bt + (size_t)(n0 + srow) * K + kbeg + sgr * 8;
  const int dwave = wid * 512;

  const int co0 = (((lane >> 4)) ^ (lane & 7)) * 8;
  const int co1 = (((lane >> 4) + 4) ^ (lane & 7)) * 8;
  const int raA = (wr * 64 + (lane & 15)) * 64;
  const int raB = (wc * 64 + (lane & 15)) * 64;

#pragma unroll
  for (int c = 0; c < 4; ++c) {
    gload_lds16(gA + (size_t)(c * 32) * K, &As[0][c * 2048 + dwave]);
    gload_lds16(gB + (size_t)(c * 32) * K, &Bs[0][c * 2048 + dwave]);
  }
#pragma unroll
  for (int c = 0; c < 4; ++c) {
    gload_lds16(gA + (size_t)(c * 32) * K + 64, &As[1][c * 2048 + dwave]);
    gload_lds16(gB + (size_t)(c * 32) * K + 64, &Bs[1][c * 2048 + dwave]);
  }
  asm volatile("s_waitcnt vmcnt(8)" ::: "memory");
  __builtin_amdgcn_s_barrier();
  __builtin_amdgcn_sched_barrier(0);

#pragma unroll 2
  for (int t = 0; t < nk; ++t) {
    const int cb = t & 1;
    const u16* Acur = &As[cb][0];
    const u16* Bcur = &Bs[cb][0];

    bf16x8 bf[4][2];
#pragma unroll
    for (int n = 0; n < 4; ++n) {
      const int ro = raB + n * 16 * 64;
      bf[n][0] = *(const bf16x8*)&Bcur[ro + co0];
      bf[n][1] = *(const bf16x8*)&Bcur[ro + co1];
    }
    bf16x8 af01[2][2];
#pragma unroll
    for (int p = 0; p < 2; ++p) {
      const int ro = raA + p * 16 * 64;
      af01[p][0] = *(const bf16x8*)&Acur[ro + co0];
      af01[p][1] = *(const bf16x8*)&Acur[ro + co1];
    }
    __builtin_amdgcn_s_setprio(1);
#pragma unroll
    for (int p = 0; p < 2; ++p)
#pragma unroll
      for (int n = 0; n < 4; ++n) {
        acc[p][n] = __builtin_amdgcn_mfma_f32_16x16x32_bf16(af01[p][0], bf[n][0], acc[p][n], 0, 0, 0);
        acc[p][n] = __builtin_amdgcn_mfma_f32_16x16x32_bf16(af01[p][1], bf[n][1], acc[p][n], 0, 0, 0);
      }
    __builtin_amdgcn_s_setprio(0);
    bf16x8 af23[2][2];
#pragma unroll
    for (int p = 0; p < 2; ++p) {
      const int ro = raA + (p + 2) * 16 * 64;
      af23[p][0] = *(const bf16x8*)&Acur[ro + co0];
      af23[p][1] = *(const bf16x8*)&Acur[ro + co1];
    }
    asm volatile("s_waitcnt lgkmcnt(0)" ::: "memory");
    __builtin_amdgcn_s_barrier();          // (1) all reads of buf[cb] retired
    if (t + 2 < nk) {
      const size_t kto = (size_t)(t + 2) * 64;
#pragma unroll
      for (int c = 0; c < 4; ++c) {
        gload_lds16(gA + (size_t)(c * 32) * K + kto, &As[cb][c * 2048 + dwave]);
        gload_lds16(gB + (size_t)(c * 32) * K + kto, &Bs[cb][c * 2048 + dwave]);
      }
    }
    __builtin_amdgcn_s_setprio(1);
#pragma unroll
    for (int p = 0; p < 2; ++p)
#pragma unroll
      for (int n = 0; n < 4; ++n) {
        acc[p + 2][n] = __builtin_amdgcn_mfma_f32_16x16x32_bf16(af23[p][0], bf[n][0], acc[p + 2][n], 0, 0, 0);
        acc[p + 2][n] = __builtin_amdgcn_mfma_f32_16x16x32_bf16(af23[p][1], bf[n][1], acc[p + 2][n], 0, 0, 0);
      }
    __builtin_amdgcn_s_setprio(0);
    if (t + 2 < nk) {
      asm volatile("s_waitcnt vmcnt(8)" ::: "memory");
    } else if (t + 1 < nk) {
      asm volatile("s_waitcnt vmcnt(0)" ::: "memory");
    }
    __builtin_amdgcn_s_barrier();          // (2) publish buf[cb^1]
    __builtin_amdgcn_sched_barrier(0);
  }

  const int z = (int)blockIdx.z;
#pragma unroll
  for (int m = 0; m < 4; ++m) {
    const int rowb = m0 + wr * 64 + m * 16 + ((lane >> 4) << 2);
#pragma unroll
    for (int n = 0; n < 4; ++n) {
      const int col = n0 + wc * 64 + n * 16 + (lane & 15);
#pragma unroll
      for (int j = 0; j < 4; ++j) {
        const int r = rowb + j;
        float v = acc[m][n][j];
        if (EPI == 0) {
          u16* outp = (u16*)C0 + (size_t)z * (2048u * 1024u);
          outp[(size_t)r * N + col] = f2b(v);
        } else if (EPI == 1) {
          const int which = col >> 10;
          const int ci = col & 1023;
          u16* outp = (u16*)((which == 0) ? C0 : (which == 1) ? C1 : C2);
          outp[((size_t)(ci >> 6) * SEQ + r) * 64 + (ci & 63)] = f2b(v);
        } else {
          float xx = v + bias[col];
          float ge = 0.5f * xx * (1.0f + erff(xx * 0.70710678118654752f));
          ((u16*)C0)[(size_t)r * N + col] = f2b(ge);
        }
      }
    }
  }
}

// ---------------------------------------------------------------------------
// Fallback logits GEMM (fp32 B, BK=32) if emb_bf16 doesn't fit ws.
// ---------------------------------------------------------------------------
__global__ __launch_bounds__(256) void gemm_f32b(
    const u16* __restrict__ A, const float* __restrict__ Bt,
    float* __restrict__ C0, int N, int K)
{
  __shared__ u16 As[128 * 32];
  __shared__ u16 Bs[128 * 32];
  const int tid = threadIdx.x;
  const int lane = tid & 63;
  const int w = tid >> 6;
  const int wr = w >> 1;
  const int wc = w & 1;

  const int T = (int)gridDim.x;
  const int bid = (int)blockIdx.x;
  const int q8 = T >> 3, r8 = T & 7;
  const int xcd = bid & 7, base = bid >> 3;
  int swz = (xcd < r8 ? xcd * (q8 + 1) : r8 * (q8 + 1) + (xcd - r8) * q8) + base;
  const int m0 = (swz & 15) * 128;
  const int n0 = (swz >> 4) * 128;

  f32x4 acc[4][4] = {};
  const u16* ga0 = A + (size_t)(m0 + w * 32 + (lane >> 2)) * K + (lane & 3) * 8;
  u16* la = &As[(w * 32) * 32];
  const float* gb32 = Bt + (size_t)(n0 + (tid >> 1)) * K + (tid & 1) * 16;
  u16* lbw = &Bs[(tid >> 1) * 32 + (tid & 1) * 16];

  for (int kt = 0; kt < K; kt += 32) {
    __syncthreads();
    gload_lds16(ga0 + kt, la);
    gload_lds16(ga0 + kt + 16 * K, la + 16 * 32);
    {
      const float4 f0 = *(const float4*)(gb32 + kt);
      const float4 f1 = *(const float4*)(gb32 + kt + 4);
      const float4 f2 = *(const float4*)(gb32 + kt + 8);
      const float4 f3 = *(const float4*)(gb32 + kt + 12);
      union { bf16x8 b; u16x8 u; } lo, hi;
      lo.b[0] = (__bf16)f0.x; lo.b[1] = (__bf16)f0.y;
      lo.b[2] = (__bf16)f0.z; lo.b[3] = (__bf16)f0.w;
      lo.b[4] = (__bf16)f1.x; lo.b[5] = (__bf16)f1.y;
      lo.b[6] = (__bf16)f1.z; lo.b[7] = (__bf16)f1.w;
      hi.b[0] = (__bf16)f2.x; hi.b[1] = (__bf16)f2.y;
      hi.b[2] = (__bf16)f2.z; hi.b[3] = (__bf16)f2.w;
      hi.b[4] = (__bf16)f3.x; hi.b[5] = (__bf16)f3.y;
      hi.b[6] = (__bf16)f3.z; hi.b[7] = (__bf16)f3.w;
      *(u16x8*)lbw = lo.u;
      *(u16x8*)(lbw + 8) = hi.u;
    }
    asm volatile("s_waitcnt vmcnt(0)" ::: "memory");
    __syncthreads();
    bf16x8 af[4], bfr[4];
#pragma unroll
    for (int m = 0; m < 4; ++m)
      af[m] = *(const bf16x8*)&As[(wr * 64 + m * 16 + (lane & 15)) * 32 + (lane >> 4) * 8];
#pragma unroll
    for (int n = 0; n < 4; ++n)
      bfr[n] = *(const bf16x8*)&Bs[(wc * 64 + n * 16 + (lane & 15)) * 32 + (lane >> 4) * 8];
#pragma unroll
    for (int m = 0; m < 4; ++m)
#pragma unroll
      for (int n = 0; n < 4; ++n)
        acc[m][n] = __builtin_amdgcn_mfma_f32_16x16x32_bf16(af[m], bfr[n], acc[m][n], 0, 0, 0);
  }

#pragma unroll
  for (int m = 0; m < 4; ++m) {
    const int rowb = m0 + wr * 64 + m * 16 + ((lane >> 4) << 2);
#pragma unroll
    for (int n = 0; n < 4; ++n) {
      const int col = n0 + wc * 64 + n * 16 + (lane & 15);
#pragma unroll
      for (int j = 0; j < 4; ++j)
        C0[(size_t)(rowb + j) * N + col] = acc[m][n][j];
    }
  }
}

// ---------------------------------------------------------------------------
// Fused embedding gather + LayerNorm: x[row] = emb[ids[row]] (fp32 copy),
// h[row] = ln(x[row])*g + b (bf16). One pass, replaces gather + ln_kernel.
// ---------------------------------------------------------------------------
__global__ __launch_bounds__(256) void ln_gather(const int* __restrict__ ids,
    const float* __restrict__ emb, float* __restrict__ x,
    const float* __restrict__ g, const float* __restrict__ b,
    u16* __restrict__ out)
{
  const int row = blockIdx.x;
  const int tid = threadIdx.x;
  const int id = ids[row];
  const float4 v = ((const float4*)(emb + (size_t)id * 1024))[tid];
  ((float4*)(x + (size_t)row * 1024))[tid] = v;
  float s = v.x + v.y + v.z + v.w;
  float sq = v.x * v.x + v.y * v.y + v.z * v.z + v.w * v.w;
#pragma unroll
  for (int o = 1; o < 64; o <<= 1) { s += __shfl_xor(s, o); sq += __shfl_xor(sq, o); }
  __shared__ float ss[4], ssq[4];
  if ((tid & 63) == 0) { ss[tid >> 6] = s; ssq[tid >> 6] = sq; }
  __syncthreads();
  s = ss[0] + ss[1] + ss[2] + ss[3];
  sq = ssq[0] + ssq[1] + ssq[2] + ssq[3];
  const float mean = s * (1.0f / 1024.0f);
  const float var = sq * (1.0f / 1024.0f) - mean * mean;
  const float rstd = rsqrtf(var + 1e-5f);
  const int c = tid * 4;
  u16* o4 = out + (size_t)row * 1024 + c;
  const float4 gg = ((const float4*)g)[tid];
  const float4 bb = ((const float4*)b)[tid];
  o4[0] = f2b((v.x - mean) * rstd * gg.x + bb.x);
  o4[1] = f2b((v.y - mean) * rstd * gg.y + bb.y);
  o4[2] = f2b((v.z - mean) * rstd * gg.z + bb.z);
  o4[3] = f2b((v.w - mean) * rstd * gg.w + bb.w);
}

// ---------------------------------------------------------------------------
// Fused residual + LayerNorm, 4 bf16 split-K partials.
// ---------------------------------------------------------------------------
__global__ __launch_bounds__(256) void ln_res4(float* __restrict__ x,
    const u16* __restrict__ P, const float* __restrict__ bias,
    const float* __restrict__ g, const float* __restrict__ b,
    u16* __restrict__ out)
{
  const int row = blockIdx.x;
  const int tid = threadIdx.x;
  const size_t off = (size_t)row * 1024;
  float4 v = ((const float4*)(x + off))[tid];
#pragma unroll
  for (int j = 0; j < 4; ++j) {
    const u16x4 a = *(const u16x4*)(P + (size_t)j * 2048 * 1024 + off + tid * 4);
    v.x += b2f(a[0]); v.y += b2f(a[1]); v.z += b2f(a[2]); v.w += b2f(a[3]);
  }
  if (bias != nullptr) {
    const float4 bi = ((const float4*)bias)[tid];
    v.x += bi.x; v.y += bi.y; v.z += bi.z; v.w += bi.w;
  }
  ((float4*)(x + off))[tid] = v;
  float s = v.x + v.y + v.z + v.w;
  float sq = v.x * v.x + v.y * v.y + v.z * v.z + v.w * v.w;
#pragma unroll
  for (int o = 1; o < 64; o <<= 1) { s += __shfl_xor(s, o); sq += __shfl_xor(sq, o); }
  __shared__ float ss[4], ssq[4];
  if ((tid & 63) == 0) { ss[tid >> 6] = s; ssq[tid >> 6] = sq; }
  __syncthreads();
  s = ss[0] + ss[1] + ss[2] + ss[3];
  sq = ssq[0] + ssq[1] + ssq[2] + ssq[3];
  const float mean = s * (1.0f / 1024.0f);
  const float var = sq * (1.0f / 1024.0f) - mean * mean;
  const float rstd = rsqrtf(var + 1e-5f);
  const int c = tid * 4;
  u16* o4 = out + off + c;
  const float4 gg = ((const float4*)g)[tid];
  const float4 bb = ((const float4*)b)[tid];
  o4[0] = f2b((v.x - mean) * rstd * gg.x + bb.x);
  o4[1] = f2b((v.y - mean) * rstd * gg.y + bb.y);
  o4[2] = f2b((v.z - mean) * rstd * gg.z + bb.z);
  o4[3] = f2b((v.w - mean) * rstd * gg.w + bb.w);
}

// ---------------------------------------------------------------------------
// Flash attention w/ ALiBi + causal (R11 config: 512 blocks x 128 threads).
// ---------------------------------------------------------------------------
__global__ __launch_bounds__(128) void attn_kernel(
    const u16* __restrict__ q, const u16* __restrict__ k, const u16* __restrict__ v,
    const float* __restrict__ slopes, u16* __restrict__ out)
{
  const int bid = (int)blockIdx.x;
  const int h = bid & 15;
  const int qi = 31 - (bid >> 4);
  const int q0 = qi * 64;
  const int tid = threadIdx.x;
  const int lane = tid & 63;
  const int w = tid >> 6;
  const float slope = slopes[h];

  __shared__ u16 Ks[2][64 * 32];
  __shared__ u16 Vt[64][72];
  __shared__ u16 Pl[2][32][72];

  const u16* qb = q + ((size_t)h * SEQ + q0 + w * 32) * 64;
  bf16x8 qf[2][2];
#pragma unroll
  for (int m = 0; m < 2; ++m)
#pragma unroll
    for (int kk = 0; kk < 2; ++kk)
      qf[m][kk] = *(const bf16x8*)(qb + (m * 16 + (lane & 15)) * 64 + kk * 32 + (lane >> 4) * 8);

  f32x4 o_acc[2][4] = {};
  float mrun[2][4], lrun[2][4];
#pragma unroll
  for (int m = 0; m < 2; ++m)
#pragma unroll
    for (int j = 0; j < 4; ++j) { mrun[m][j] = -1e30f; lrun[m][j] = 0.0f; }

  const int ntiles = qi + 1;
  const int wmaxrow = q0 + w * 32 + 31;

  const int ksl = (lane & 3) ^ ((lane >> 2) & 3);
  const u16* gk0 = k + ((size_t)h * SEQ + (lane >> 2)) * 64 + w * 32 + ksl * 8;
  u16* lk = &Ks[w][0];
  const u16* gv0 = v + ((size_t)h * SEQ + lane) * 64 + w * 32;
  const int krd = ((lane >> 4) ^ (lane & 3)) * 8;

  for (int t = 0; t < ntiles; ++t) {
    const int j0 = t << 6;
    __syncthreads();
#pragma unroll
    for (int r = 0; r < 4; ++r)
      gload_lds16(gk0 + (size_t)(j0 + r * 16) * 64, lk + r * 16 * 32);
    {
      const u16* gvp = gv0 + (size_t)j0 * 64;
      u16x8 v0 = *(const u16x8*)gvp;
      u16x8 v1 = *(const u16x8*)(gvp + 8);
      u16x8 v2 = *(const u16x8*)(gvp + 16);
      u16x8 v3 = *(const u16x8*)(gvp + 24);
      const int d0 = w * 32;
#pragma unroll
      for (int i = 0; i < 8; ++i) Vt[d0 + i][lane] = v0[i];
#pragma unroll
      for (int i = 0; i < 8; ++i) Vt[d0 + 8 + i][lane] = v1[i];
#pragma unroll
      for (int i = 0; i < 8; ++i) Vt[d0 + 16 + i][lane] = v2[i];
#pragma unroll
      for (int i = 0; i < 8; ++i) Vt[d0 + 24 + i][lane] = v3[i];
    }
    asm volatile("s_waitcnt vmcnt(0)" ::: "memory");
    __syncthreads();

    if (wmaxrow >= j0) {
      f32x4 s[2][4] = {};
      __builtin_amdgcn_s_setprio(1);
#pragma unroll
      for (int kk = 0; kk < 2; ++kk) {
        bf16x8 kf[4];
#pragma unroll
        for (int n = 0; n < 4; ++n)
          kf[n] = *(const bf16x8*)&Ks[kk][(n * 16 + (lane & 15)) * 32 + krd];
#pragma unroll
        for (int m = 0; m < 2; ++m)
#pragma unroll
          for (int n = 0; n < 4; ++n)
            s[m][n] = __builtin_amdgcn_mfma_f32_16x16x32_bf16(qf[m][kk], kf[n], s[m][n], 0, 0, 0);
      }
      __builtin_amdgcn_s_setprio(0);
      const int rq = q0 + w * 32 + ((lane >> 4) << 2);
      const int ck = j0 + (lane & 15);
#pragma unroll
      for (int m = 0; m < 2; ++m) {
#pragma unroll
        for (int j = 0; j < 4; ++j) {
          const int qi2 = rq + m * 16 + j;
          float mx = -1e30f;
#pragma unroll
          for (int n = 0; n < 4; ++n) {
            const int kj = ck + n * 16;
            float val = s[m][n][j] * 0.125f - slope * (float)(kj - qi2);
            val = (kj <= qi2) ? val : -1e30f;
            s[m][n][j] = val;
            mx = fmaxf(mx, val);
          }
#pragma unroll
          for (int o = 1; o < 16; o <<= 1) mx = fmaxf(mx, __shfl_xor(mx, o));
          const float mnew = fmaxf(mrun[m][j], mx);
          const float alpha = __expf(mrun[m][j] - mnew);
          mrun[m][j] = mnew;
          float rs = 0.0f;
          const int prow = m * 16 + ((lane >> 4) << 2) + j;
#pragma unroll
          for (int n = 0; n < 4; ++n) {
            const float p = __expf(s[m][n][j] - mnew);
            rs += p;
            Pl[w][prow][n * 16 + (lane & 15)] = f2b(p);
          }
#pragma unroll
          for (int o = 1; o < 16; o <<= 1) rs += __shfl_xor(rs, o);
          lrun[m][j] = lrun[m][j] * alpha + rs;
#pragma unroll
          for (int n = 0; n < 4; ++n) o_acc[m][n][j] *= alpha;
        }
      }
      __builtin_amdgcn_s_setprio(1);
#pragma unroll
      for (int kk = 0; kk < 2; ++kk) {
        bf16x8 pf[2], vf[4];
#pragma unroll
        for (int m = 0; m < 2; ++m)
          pf[m] = *(const bf16x8*)&Pl[w][m * 16 + (lane & 15)][kk * 32 + (lane >> 4) * 8];
#pragma unroll
        for (int n = 0; n < 4; ++n)
          vf[n] = *(const bf16x8*)&Vt[n * 16 + (lane & 15)][kk * 32 + (lane >> 4) * 8];
#pragma unroll
        for (int m = 0; m < 2; ++m)
#pragma unroll
          for (int n = 0; n < 4; ++n)
            o_acc[m][n] = __builtin_amdgcn_mfma_f32_16x16x32_bf16(pf[m], vf[n], o_acc[m][n], 0, 0, 0);
      }
      __builtin_amdgcn_s_setprio(0);
    }
  }

#pragma unroll
  for (int m = 0; m < 2; ++m) {
    const int sbase = q0 + w * 32 + m * 16 + ((lane >> 4) << 2);
#pragma unroll
    for (int n = 0; n < 4; ++n) {
      const int d = h * 64 + n * 16 + (lane & 15);
#pragma unroll
      for (int j = 0; j < 4; ++j)
        out[(size_t)(sbase + j) * 1024 + d] = f2b(o_acc[m][n][j] / lrun[m][j]);
    }
  }
}

// ---------------------------------------------------------------------------
extern "C" void kernel_launch(void* const* d_in, const int* in_sizes, int n_in,
                              void* d_out, int out_size, void* d_ws, size_t ws_size,
                              hipStream_t stream)
{
  (void)in_sizes; (void)n_in; (void)out_size;
  const int* ids = (const int*)d_in[0];
  const float* emb = (const float*)d_in[1];
  const float* slopes = (const float*)d_in[2];
  const float* Wq = (const float*)d_in[3];
  const float* Wk = (const float*)d_in[4];
  const float* Wv = (const float*)d_in[5];
  const float* Wo = (const float*)d_in[6];
  const float* W1 = (const float*)d_in[7];
  const float* b1 = (const float*)d_in[8];
  const float* W2 = (const float*)d_in[9];
  const float* b2 = (const float*)d_in[10];
  const float* g1 = (const float*)d_in[11];
  const float* be1 = (const float*)d_in[12];
  const float* g2 = (const float*)d_in[13];
  const float* be2 = (const float*)d_in[14];
  const float* gf = (const float*)d_in[15];
  const float* bfin = (const float*)d_in[16];

  char* ob = (char*)d_out;
  float* x    = (float*)ob;                          // 8 MB fp32 residual
  u16* qb     = (u16*)(ob + (size_t)( 8u << 20));    // 4 MB
  u16* kb     = (u16*)(ob + (size_t)(12u << 20));    // 4 MB
  u16* vb     = (u16*)(ob + (size_t)(16u << 20));    // 4 MB
  u16* attn   = (u16*)(ob + (size_t)(20u << 20));    // 4 MB
  u16* ff     = (u16*)(ob + (size_t)(24u << 20));    // 16 MB
  u16* Wqkv_b = (u16*)(ob + (size_t)( 40u << 20));   // 24 MB  [4][3072][1024]
  u16* Wo_b   = (u16*)(ob + (size_t)( 64u << 20));   // 8 MB
  u16* W1_b   = (u16*)(ob + (size_t)( 72u << 20));   // 32 MB
  u16* W2_b   = (u16*)(ob + (size_t)(104u << 20));   // 32 MB
  u16* P      = (u16*)(ob + (size_t)(136u << 20));   // 16 MB: 4 bf16 partials
  u16* h      = (u16*)d_ws;                          // 4 MB
  const size_t emb_b_need = (size_t)(4u << 20) + (size_t)32000 * 1024 * 2;
  const bool emb_fits = ws_size >= emb_b_need;
  u16* emb_b = (u16*)((char*)d_ws + (4u << 20));
  float* logits = (float*)d_out;

  {
    CvtArgs a;
    const u32 wsz = 4 * 1024 * 1024 / 8;
    const u32 fsz = 16 * 1024 * 1024 / 8;
    const u32 esz = 32000 * 1024 / 8;
    a.src[0] = Wq; a.dst[0] = Wqkv_b;
    a.src[1] = Wk; a.dst[1] = Wqkv_b + 1024 * 1024;
    a.src[2] = Wv; a.dst[2] = Wqkv_b + 2 * 1024 * 1024;
    a.src[3] = Wo; a.dst[3] = Wo_b;
    a.src[4] = W1; a.dst[4] = W1_b;
    a.src[5] = W2; a.dst[5] = W2_b;
    a.src[6] = emb; a.dst[6] = emb_b;
    a.beg[0] = 0;
    a.beg[1] = wsz;      a.beg[2] = 2 * wsz;  a.beg[3] = 3 * wsz;
    a.beg[4] = 4 * wsz;  a.beg[5] = 4 * wsz + fsz;  a.beg[6] = 4 * wsz + 2 * fsz;
    a.beg[7] = a.beg[6] + esz;
    a.total = emb_fits ? a.beg[7] : a.beg[6];
    cvt_all<<<2048, 256, 0, stream>>>(a);
  }

  ln_gather<<<2048, 256, 0, stream>>>(ids, emb, x, g1, be1, h);

  for (int l = 0; l < 4; ++l) {
    const size_t wqkv = (size_t)l * 3072 * 1024;
    const size_t wo = (size_t)l * 1024 * 1024;
    const size_t wf = (size_t)l * 4096 * 1024;
    gemm128p<1><<<dim3(384, 1, 1), 256, 0, stream>>>(h, Wqkv_b + wqkv,
        qb, kb, vb, nullptr, 3072, 1024);
    attn_kernel<<<dim3(512, 1, 1), 128, 0, stream>>>(qb, kb, vb, slopes, attn);
    gemm128p<0><<<dim3(128, 1, 4), 256, 0, stream>>>(attn, Wo_b + wo,
        P, nullptr, nullptr, nullptr, 1024, 1024);
    ln_res4<<<2048, 256, 0, stream>>>(x, P, nullptr,
        g2 + l * 1024, be2 + l * 1024, h);
    gemm128p<2><<<dim3(512, 1, 1), 256, 0, stream>>>(h, W1_b + wf,
        ff, nullptr, nullptr, b1 + l * 4096, 4096, 1024);
    gemm128p<0><<<dim3(128, 1, 4), 256, 0, stream>>>(ff, W2_b + wf,
        P, nullptr, nullptr, nullptr, 1024, 4096);
    if (l < 3) {
      ln_res4<<<2048, 256, 0, stream>>>(x, P, b2 + l * 1024,
          g1 + (l + 1) * 1024, be1 + (l + 1) * 1024, h);
    } else {
      ln_res4<<<2048, 256, 0, stream>>>(x, P, b2 + l * 1024, gf, bfin, h);
    }
  }

  if (emb_fits) {
    gemm256<<<dim3(1000, 1, 1), 512, 0, stream>>>(h, emb_b, logits, 32000, 1024);
  } else {
    gemm_f32b<<<dim3(4000, 1, 1), 256, 0, stream>>>(h, emb, logits, 32000, 1024);
  }
}